// Round 6
// baseline (377.212 us; speedup 1.0000x reference)
//
#include <hip/hip_runtime.h>
#include <hip/hip_bf16.h>

#define T_TOK 2048   // BATCH*SEQLEN
#define LSEQ  1024
#define DM    1024
#define DI    2048
#define LDW2  72     // LDS row stride for K=64 dt gemm

using bf16 = __hip_bfloat16;
typedef __attribute__((ext_vector_type(8))) short short8;
typedef __attribute__((ext_vector_type(4))) short short4b;
typedef __attribute__((ext_vector_type(4))) float floatx4;

__device__ inline float to_f(float v) { return v; }
__device__ inline float to_f(bf16 v) { return __bfloat162float(v); }
__device__ inline bf16  f2bf(float v) { return __float2bfloat16(v); }
__device__ inline float bf2f(short s) { return __bfloat162float(__builtin_bit_cast(bf16, s)); }

// load 8 contiguous elements as bf16 bit-pattern (converting if fp32 source)
__device__ inline short8 ld8(const bf16* p) { return *(const short8*)p; }
__device__ inline short8 ld8(const float* p) {
    floatx4 f0 = *(const floatx4*)p;
    floatx4 f1 = *(const floatx4*)(p + 4);
    short8 r;
#pragma unroll
    for (int i = 0; i < 4; ++i) {
        r[i]     = __builtin_bit_cast(short, __float2bfloat16(f0[i]));
        r[i + 4] = __builtin_bit_cast(short, __float2bfloat16(f1[i]));
    }
    return r;
}

// async global->LDS, 16B per lane (dest = wave-uniform base + lane*16)
__device__ __forceinline__ void gload16(const void* g, void* l) {
    __builtin_amdgcn_global_load_lds(
        (const __attribute__((address_space(1))) unsigned int*)g,
        (__attribute__((address_space(3))) unsigned int*)l, 16, 0, 0);
}

// Linear [row][32] bf16 tile with XOR involution on the 16B slot index:
// col ^= ((row>>1)&3)<<3.  Combined with row*16-dword stride (parity from
// row bit0), each quarter-wave of a ds_read_b128 hits each 4-bank set with
// exactly 2 lanes -> conflict-free.  Same XOR applied to the GLOBAL source
// column during staging (linear dest, pre-swizzled source).
__device__ __forceinline__ int swz32(int row, int col) {
    return row * 32 + (col ^ (((row >> 1) & 3) << 3));
}

// ---------------------------------------------------------------------------
// GEMM core: C[M,N] = A[M,K] @ W[N,K]^T, both bf16. 128x128 tile, BK=32,
// 4 waves (2x2 of 64x64), 16x16x32 MFMA, global_load_lds(16B) staging into
// DOUBLE-BUFFERED LDS with the T3 minimum-2-phase schedule:
//   STAGE(buf^1, k+32) ; compute(buf) ; s_waitcnt vmcnt(0) ; raw s_barrier
// One barrier per K-step; the next tile's HBM latency hides under the
// current tile's ds_read+MFMA (same-wave hiding — essential at 2 blocks/CU
// where __syncthreads()'s vmcnt(0) drain would expose it every step).
// EPI: 0 bf16 | 2 bf16 softplus(c+bias) | 4 bf16 relu(c+bias)
//      7 fp32 partial @ +bz*zstr | 8 bf16 partial @ +bz*zstr
// ---------------------------------------------------------------------------
template<int EPI, int KS>
__device__ __forceinline__ void gemm_core(
    const bf16* __restrict__ A, int lda,
    const bf16* __restrict__ W, int K,
    float* __restrict__ outF, bf16* __restrict__ outB, int ldc,
    const float* __restrict__ bias, size_t zstr)
{
    __shared__ __align__(16) bf16 sA[2][128 * 32];
    __shared__ __align__(16) bf16 sW[2][128 * 32];
    const int tid  = threadIdx.x;
    const int lane = tid & 63, wid = tid >> 6;

    // bijective chunked XCD swizzle (all grids have nwg % 8 == 0)
    const int nwg = gridDim.x * gridDim.y * gridDim.z;
    const int lin = blockIdx.x + gridDim.x * (blockIdx.y + gridDim.y * blockIdx.z);
    const int sid = (lin & 7) * (nwg >> 3) + (lin >> 3);
    const int bx  = sid % gridDim.x;
    const int byz = sid / gridDim.x;
    const int by  = byz % gridDim.y;
    const int bz  = byz / gridDim.y;

    const int m0 = bx * 128, n0 = by * 128;
    const int wm = (wid >> 1) * 64, wn = (wid & 1) * 64;
    const int lr = lane & 15, lh = lane >> 4;

    const int r0  = tid >> 2;
    const int gc0 = ((tid & 3) * 8) ^ (((r0 >> 1) & 3) << 3);

    const int kBeg = bz * (K / KS);
    const int kEnd = kBeg + K / KS;

    const bf16* aR0 = A + (size_t)(m0 + r0)      * lda + gc0;
    const bf16* aR1 = A + (size_t)(m0 + r0 + 64) * lda + gc0;
    const bf16* wR0 = W + (size_t)(n0 + r0)      * K   + gc0;
    const bf16* wR1 = W + (size_t)(n0 + r0 + 64) * K   + gc0;

    floatx4 acc[4][4];
#pragma unroll
    for (int i = 0; i < 4; ++i)
#pragma unroll
        for (int j = 0; j < 4; ++j) acc[i][j] = (floatx4){0.f, 0.f, 0.f, 0.f};

#define STAGE(B, KK) do {                                       \
        gload16(aR0 + (KK), &sA[B][wid * 512]);                 \
        gload16(aR1 + (KK), &sA[B][2048 + wid * 512]);          \
        gload16(wR0 + (KK), &sW[B][wid * 512]);                 \
        gload16(wR1 + (KK), &sW[B][2048 + wid * 512]);          \
    } while (0)

#define COMPUTE(B) do {                                                        \
        short8 af[4], wf[4];                                                   \
        _Pragma("unroll")                                                      \
        for (int i = 0; i < 4; ++i)                                            \
            af[i] = *(const short8*)(&sA[B][swz32(wm + i * 16 + lr, lh * 8)]); \
        _Pragma("unroll")                                                      \
        for (int j = 0; j < 4; ++j)                                            \
            wf[j] = *(const short8*)(&sW[B][swz32(wn + j * 16 + lr, lh * 8)]); \
        _Pragma("unroll")                                                      \
        for (int i = 0; i < 4; ++i)                                            \
            _Pragma("unroll")                                                  \
            for (int j = 0; j < 4; ++j)                                        \
                acc[i][j] = __builtin_amdgcn_mfma_f32_16x16x32_bf16(           \
                    af[i], wf[j], acc[i][j], 0, 0, 0);                         \
    } while (0)

#define PHASE_SYNC() do {                                       \
        __builtin_amdgcn_sched_barrier(0);                      \
        asm volatile("s_waitcnt vmcnt(0)" ::: "memory");        \
        __builtin_amdgcn_s_barrier();                           \
        __builtin_amdgcn_sched_barrier(0);                      \
    } while (0)

    // prologue: stage tile kBeg into buf0
    STAGE(0, kBeg);
    PHASE_SYNC();

    for (int k0 = kBeg; k0 < kEnd; k0 += 64) {
        // phase A: stage k0+32 -> buf1 ; compute buf0
        STAGE(1, k0 + 32);
        COMPUTE(0);
        PHASE_SYNC();
        // phase B: stage k0+64 (wrap = dummy) -> buf0 ; compute buf1
        int kn = (k0 + 64 < kEnd) ? k0 + 64 : kBeg;
        STAGE(0, kn);
        COMPUTE(1);
        PHASE_SYNC();
    }
#undef STAGE
#undef COMPUTE
#undef PHASE_SYNC

    // epilogue: C/D layout col=lane&15, row=(lane>>4)*4+reg
#pragma unroll
    for (int i = 0; i < 4; ++i) {
#pragma unroll
        for (int j = 0; j < 4; ++j) {
#pragma unroll
            for (int r = 0; r < 4; ++r) {
                int row = m0 + wm + i * 16 + lh * 4 + r;
                int col = n0 + wn + j * 16 + lr;
                size_t off = (size_t)row * ldc + col;
                float c = acc[i][j][r];
                if (EPI == 0) {
                    outB[off] = f2bf(c);
                } else if (EPI == 2) {
                    float v = c + bias[col];
                    outB[off] = f2bf((v > 15.f) ? v : log1pf(__expf(v)));
                } else if (EPI == 4) {
                    float v = c + bias[col];
                    outB[off] = f2bf(v > 0.f ? v : 0.f);
                } else if (EPI == 7) {
                    outF[off + (size_t)bz * zstr] = c;
                } else if (EPI == 8) {
                    outB[off + (size_t)bz * zstr] = f2bf(c);
                }
            }
        }
    }
}

// named wrappers (distinct symbols -> distinct rocprof rows)
__launch_bounds__(256, 3)
__global__ void g_inproj(const bf16* __restrict__ A, const bf16* __restrict__ W,
                         bf16* __restrict__ outB)
{ gemm_core<0, 1>(A, DM, W, DM, nullptr, outB, 4096, nullptr, 0); }

__launch_bounds__(256, 3)
__global__ void g_xproj(const bf16* __restrict__ A, const bf16* __restrict__ W,
                        float* __restrict__ outF)
{ gemm_core<7, 16>(A, DI, W, DI, outF, nullptr, 128, nullptr, (size_t)T_TOK * 128); }

__launch_bounds__(256, 3)
__global__ void g_outproj(const bf16* __restrict__ A, const bf16* __restrict__ W,
                          bf16* __restrict__ outB)
{ gemm_core<8, 4>(A, DI, W, DI, nullptr, outB, DM, nullptr, (size_t)T_TOK * DM); }

__launch_bounds__(256, 3)
__global__ void g_ffn1(const bf16* __restrict__ A, const bf16* __restrict__ W,
                       bf16* __restrict__ outB, const float* __restrict__ bias)
{ gemm_core<4, 1>(A, DM, W, DM, nullptr, outB, 4096, bias, 0); }

__launch_bounds__(256, 3)
__global__ void g_ffn2_4(const bf16* __restrict__ A, const bf16* __restrict__ W,
                         bf16* __restrict__ outB)
{ gemm_core<8, 4>(A, 4096, W, 4096, nullptr, outB, DM, nullptr, (size_t)T_TOK * DM); }

__launch_bounds__(256, 3)
__global__ void g_ffn2_2(const bf16* __restrict__ A, const bf16* __restrict__ W,
                         bf16* __restrict__ outB)
{ gemm_core<8, 2>(A, 4096, W, 4096, nullptr, outB, DM, nullptr, (size_t)T_TOK * DM); }

// fp32 -> bf16 weight conversion (8 elems/thread)
__launch_bounds__(256)
__global__ void cvtw(const float* __restrict__ src, bf16* __restrict__ dst)
{
    size_t i = ((size_t)blockIdx.x * 256 + threadIdx.x) * 8;
    *(short8*)(dst + i) = ld8(src + i);
}

// fused 4-array weight conversion + x_proj pad (roomy mode; one launch)
__launch_bounds__(256)
__global__ void cvtw5(const float* __restrict__ s0, bf16* __restrict__ d0,
                      const float* __restrict__ s1, bf16* __restrict__ d1,
                      const float* __restrict__ s2, bf16* __restrict__ d2,
                      const float* __restrict__ s3, bf16* __restrict__ d3,
                      const float* __restrict__ s4, bf16* __restrict__ d4)
{
    constexpr size_t N0 = (size_t)2 * DI * DM;   // in_proj
    constexpr size_t N1 = (size_t)DM * DI;       // out_w
    constexpr size_t N2 = (size_t)4 * DM * DM;   // fw1
    constexpr size_t N3 = (size_t)DM * 4 * DM;   // fw2
    size_t i = ((size_t)blockIdx.x * 256 + threadIdx.x) * 8;
    if (i < N0) { *(short8*)(d0 + i) = ld8(s0 + i); return; }
    i -= N0;
    if (i < N1) { *(short8*)(d1 + i) = ld8(s1 + i); return; }
    i -= N1;
    if (i < N2) { *(short8*)(d2 + i) = ld8(s2 + i); return; }
    i -= N2;
    if (i < N3) { *(short8*)(d3 + i) = ld8(s3 + i); return; }
    i -= N3;
    // x_proj pad: [96,2048] fp32 -> [128,2048] bf16, zero rows >= 96
    int row = (int)(i >> 11);
    if (row < 96) { *(short8*)(d4 + i) = ld8(s4 + i); }
    else { *(short8*)(d4 + i) = (short8){0,0,0,0,0,0,0,0}; }
}

// ---------------------------------------------------------------------------
// dt GEMM, specialized: dtb = softplus(xdf[:, :64] @ dt_w^T + dt_b)
// M=2048, N=2048, K=64. BM=32, BN=128 -> grid (64,16)=1024 blocks.
// ---------------------------------------------------------------------------
__launch_bounds__(256)
__global__ void gemm_dt64(const float* __restrict__ A,   // xdf [2048,128]
                          const float* __restrict__ W,   // dt_w [2048,64]
                          const float* __restrict__ bias,
                          bf16* __restrict__ outB)       // dtb [2048,2048]
{
    __shared__ __align__(16) bf16 sA[32 * LDW2];
    __shared__ __align__(16) bf16 sW[128 * LDW2];
    const int tid = threadIdx.x;
    const int lane = tid & 63, w = tid >> 6;
    const int m0 = blockIdx.x * 32, n0 = blockIdx.y * 128;

    {   // stage A: 32 rows x 64 cols (1 ld8/thread)
        int ar = tid >> 3, ac = (tid & 7) * 8;
        *(short8*)(sA + ar * LDW2 + ac) = ld8(A + (size_t)(m0 + ar) * 128 + ac);
        // stage W: 128 rows x 64 cols (4 ld8/thread)
        int wr = tid >> 1, wc = (tid & 1) * 32;
        const float* wp = W + (size_t)(n0 + wr) * 64 + wc;
        *(short8*)(sW + wr * LDW2 + wc)      = ld8(wp);
        *(short8*)(sW + wr * LDW2 + wc + 8)  = ld8(wp + 8);
        *(short8*)(sW + wr * LDW2 + wc + 16) = ld8(wp + 16);
        *(short8*)(sW + wr * LDW2 + wc + 24) = ld8(wp + 24);
    }
    __syncthreads();

    const int lr = lane & 15, lh = lane >> 4;
    floatx4 acc[2][2];
#pragma unroll
    for (int i = 0; i < 2; ++i)
#pragma unroll
        for (int j = 0; j < 2; ++j) acc[i][j] = (floatx4){0.f, 0.f, 0.f, 0.f};

#pragma unroll
    for (int kk = 0; kk < 2; ++kk) {
        short8 af[2], wf[2];
#pragma unroll
        for (int i = 0; i < 2; ++i)
            af[i] = *(const short8*)(sA + (i * 16 + lr) * LDW2 + kk * 32 + lh * 8);
#pragma unroll
        for (int j = 0; j < 2; ++j)
            wf[j] = *(const short8*)(sW + (w * 32 + j * 16 + lr) * LDW2 + kk * 32 + lh * 8);
#pragma unroll
        for (int i = 0; i < 2; ++i)
#pragma unroll
            for (int j = 0; j < 2; ++j)
                acc[i][j] = __builtin_amdgcn_mfma_f32_16x16x32_bf16(af[i], wf[j], acc[i][j], 0, 0, 0);
    }

#pragma unroll
    for (int i = 0; i < 2; ++i) {
#pragma unroll
        for (int j = 0; j < 2; ++j) {
#pragma unroll
            for (int r = 0; r < 4; ++r) {
                int row = m0 + i * 16 + lh * 4 + r;
                int col = n0 + w * 32 + j * 16 + lr;
                float v = acc[i][j][r] + bias[col];
                outB[(size_t)row * DI + col] = f2bf((v > 15.f) ? v : log1pf(__expf(v)));
            }
        }
    }
}

// sum 16 split-K fp32 partial slices -> xdf
__launch_bounds__(256)
__global__ void reduce16(const float* __restrict__ P, float* __restrict__ out)
{
    int i = blockIdx.x * 256 + threadIdx.x;            // float4 idx, 65536 total
    const floatx4* P4 = (const floatx4*)P;
    floatx4 s = (floatx4){0.f, 0.f, 0.f, 0.f};
#pragma unroll
    for (int z = 0; z < 16; ++z) s += P4[(size_t)z * 65536 + i];
    ((floatx4*)out)[i] = s;
}

// Fused: x2 = x + sum_{z<4} P[z] ; h1 = LayerNorm(x2; g,b).  Block per token.
__launch_bounds__(256)
__global__ void red4_ln(const bf16* __restrict__ P, const float* __restrict__ x,
                        const float* __restrict__ g, const float* __restrict__ bb,
                        float* __restrict__ x2, bf16* __restrict__ h1)
{
    int t = blockIdx.x, tid = threadIdx.x;
    size_t rowoff = (size_t)t * DM + tid * 4;
    floatx4 xv = *(const floatx4*)(x + rowoff);
    float v[4];
#pragma unroll
    for (int i = 0; i < 4; ++i) v[i] = xv[i];
#pragma unroll
    for (int z = 0; z < 4; ++z) {
        short4b p = *(const short4b*)(P + (size_t)z * T_TOK * DM + rowoff);
#pragma unroll
        for (int i = 0; i < 4; ++i) v[i] += bf2f(p[i]);
    }
    *(floatx4*)(x2 + rowoff) = (floatx4){v[0], v[1], v[2], v[3]};
    float s = v[0] + v[1] + v[2] + v[3];
    float ss = v[0]*v[0] + v[1]*v[1] + v[2]*v[2] + v[3]*v[3];
#pragma unroll
    for (int o = 1; o < 64; o <<= 1) { s += __shfl_xor(s, o); ss += __shfl_xor(ss, o); }
    __shared__ float red[8];
    int lane = tid & 63, wid = tid >> 6;
    if (lane == 0) { red[wid] = s; red[wid + 4] = ss; }
    __syncthreads();
    s  = red[0] + red[1] + red[2] + red[3];
    ss = red[4] + red[5] + red[6] + red[7];
    float mu  = s * (1.f / DM);
    float var = ss * (1.f / DM) - mu * mu;
    float rs  = rsqrtf(var + 1e-5f);
    int c = tid * 4;
    short4b o4;
#pragma unroll
    for (int i = 0; i < 4; ++i)
        o4[i] = __builtin_bit_cast(short, f2bf((v[i] - mu) * rs * g[c + i] + bb[c + i]));
    *(short4b*)(h1 + rowoff) = o4;
}

// out = bias[col] + resid + sum_{z<Z} P[z]
template<int Z>
__launch_bounds__(256)
__global__ void red_bias_resid(const bf16* __restrict__ P, const float* __restrict__ bias,
                               const float* __restrict__ resid, float* __restrict__ out)
{
    size_t base = ((size_t)blockIdx.x * 256 + threadIdx.x) * 8;
    int c = (int)(base & (DM - 1));
    floatx4 b0 = *(const floatx4*)(bias + c);
    floatx4 b1 = *(const floatx4*)(bias + c + 4);
    floatx4 x0 = *(const floatx4*)(resid + base);
    floatx4 x1 = *(const floatx4*)(resid + base + 4);
    float s[8];
#pragma unroll
    for (int j = 0; j < 4; ++j) { s[j] = x0[j] + b0[j]; s[j + 4] = x1[j] + b1[j]; }
#pragma unroll
    for (int z = 0; z < Z; ++z) {
        short8 p = *(const short8*)(P + (size_t)z * T_TOK * DM + base);
#pragma unroll
        for (int j = 0; j < 8; ++j) s[j] += bf2f(p[j]);
    }
    *(floatx4*)(out + base)     = (floatx4){s[0], s[1], s[2], s[3]};
    *(floatx4*)(out + base + 4) = (floatx4){s[4], s[5], s[6], s[7]};
}

// ---------------------------------------------------------------------------
// LayerNorm over 1024 dims (fp32 in/params), one block per token, bf16 out
// ---------------------------------------------------------------------------
__launch_bounds__(256)
__global__ void ln_kernel(const float* __restrict__ x, const float* __restrict__ g,
                          const float* __restrict__ bb, bf16* __restrict__ out)
{
    int t = blockIdx.x, tid = threadIdx.x;
    const float* xr = x + (size_t)t * DM;
    float v[4], s = 0.f, ss = 0.f;
#pragma unroll
    for (int i = 0; i < 4; ++i) {
        v[i] = xr[tid + i * 256];
        s += v[i]; ss += v[i] * v[i];
    }
#pragma unroll
    for (int o = 1; o < 64; o <<= 1) { s += __shfl_xor(s, o); ss += __shfl_xor(ss, o); }
    __shared__ float red[8];
    int lane = tid & 63, wid = tid >> 6;
    if (lane == 0) { red[wid] = s; red[wid + 4] = ss; }
    __syncthreads();
    s  = red[0] + red[1] + red[2] + red[3];
    ss = red[4] + red[5] + red[6] + red[7];
    float mu  = s * (1.f / DM);
    float var = ss * (1.f / DM) - mu * mu;
    float rs  = rsqrtf(var + 1e-5f);
#pragma unroll
    for (int i = 0; i < 4; ++i) {
        int c = tid + i * 256;
        out[(size_t)t * DM + c] = f2bf((v[i] - mu) * rs * g[c] + bb[c]);
    }
}

// ---------------------------------------------------------------------------
// depthwise causal conv (k=4, fp32 weights) + bias + SiLU -> bf16.
// Vectorized: 8 consecutive d per thread (4x short8 loads, 1x short8 store).
// ---------------------------------------------------------------------------
__launch_bounds__(256)
__global__ void conv_silu(const bf16* __restrict__ xz, const float* __restrict__ cw,
                          const float* __restrict__ cb, bf16* __restrict__ xcb)
{
    int idx = (blockIdx.x * 256 + threadIdx.x) * 8;   // T_TOK*DI elems
    int d  = idx & (DI - 1);
    int tk = idx >> 11;
    int t  = tk & (LSEQ - 1);
    const short8 zero = {0, 0, 0, 0, 0, 0, 0, 0};
    short8 x3 = ld8(xz + (size_t)tk * 4096 + d);
    short8 x2 = (t >= 1) ? ld8(xz + (size_t)(tk - 1) * 4096 + d) : zero;
    short8 x1 = (t >= 2) ? ld8(xz + (size_t)(tk - 2) * 4096 + d) : zero;
    short8 x0 = (t >= 3) ? ld8(xz + (size_t)(tk - 3) * 4096 + d) : zero;
    short8 r;
#pragma unroll
    for (int j = 0; j < 8; ++j) {
        floatx4 wv = *(const floatx4*)(cw + (size_t)(d + j) * 4);
        float acc = cb[d + j]
                  + wv[0] * bf2f(x0[j]) + wv[1] * bf2f(x1[j])
                  + wv[2] * bf2f(x2[j]) + wv[3] * bf2f(x3[j]);
        float s = acc / (1.f + __expf(-acc));
        r[j] = __builtin_bit_cast(short, f2bf(s));
    }
    *(short8*)(xcb + idx) = r;
}

// pad x_proj_w fp32 [96,2048] -> bf16 [128,2048] with zero rows (tight mode)
__launch_bounds__(256)
__global__ void padw_kernel(const float* __restrict__ w, bf16* __restrict__ wp)
{
    int idx = blockIdx.x * 256 + threadIdx.x;   // 128*2048
    int row = idx >> 11;
    wp[idx] = (row < 96) ? f2bf(w[idx]) : f2bf(0.f);
}

// ---------------------------------------------------------------------------
// Chunked selective scan, 3 phases, 8 states per thread (2 threads per (b,d)
// chain). Template NCH_: chunk count (roomy=64 for 8 blocks/CU TLP).
// ---------------------------------------------------------------------------
template<int NCH_>
__launch_bounds__(256)
__global__ void scan_part1(const bf16* __restrict__ dt, const bf16* __restrict__ xc,
                           const float* __restrict__ xdbl, const float* __restrict__ A_log,
                           float* __restrict__ Ssum, float* __restrict__ hend)
{
    constexpr int CLEN_ = LSEQ / NCH_;
    constexpr int LOGN  = (NCH_ == 64) ? 6 : 5;
    int G = blockIdx.x * 256 + threadIdx.x;     // 2 * NCH_ * DI * 2
    int half = G & 1;
    int d = (G >> 1) & (DI - 1);
    int c = (G >> 12) & (NCH_ - 1);
    int b = G >> (12 + LOGN);
    int n0 = half * 8;

    floatx4 al0 = *(const floatx4*)(A_log + d * 16 + n0);
    floatx4 al1 = *(const floatx4*)(A_log + d * 16 + n0 + 4);
    float a[8];
#pragma unroll
    for (int j = 0; j < 4; ++j) { a[j] = -__expf(al0[j]); a[j + 4] = -__expf(al1[j]); }

    const bf16*  dt_p = dt   + (size_t)b * LSEQ * DI + d;
    const bf16*  xc_p = xc   + (size_t)b * LSEQ * DI + d;
    const float* xb_p = xdbl + (size_t)b * LSEQ * 128 + 64 + n0;   // B slice

    float h[8];
#pragma unroll
    for (int j = 0; j < 8; ++j) h[j] = 0.f;
    float S = 0.f;

    const int t0 = c * CLEN_;
#pragma unroll 4
    for (int t = t0; t < t0 + CLEN_; ++t) {
        float dtv = to_f(dt_p[(size_t)t * DI]);
        float xv  = to_f(xc_p[(size_t)t * DI]);
        floatx4 B0 = *(const floatx4*)(xb_p + (size_t)t * 128);
        floatx4 B1 = *(const floatx4*)(xb_p + (size_t)t * 128 + 4);
        S += dtv;
        float dx = dtv * xv;
#pragma unroll
        for (int j = 0; j < 4; ++j) {
            h[j]     = fmaf(__expf(dtv * a[j]),     h[j],     dx * B0[j]);
            h[j + 4] = fmaf(__expf(dtv * a[j + 4]), h[j + 4], dx * B1[j]);
        }
    }

    size_t cid = (size_t)(b * NCH_ + c) * DI + d;
    if (half == 0) Ssum[cid] = S;
    float* he = hend + cid * 16 + n0;
    *(floatx4*)he       = (floatx4){h[0], h[1], h[2], h[3]};
    *(floatx4*)(he + 4) = (floatx4){h[4], h[5], h[6], h[7]};
}

template<int NCH_>
__launch_bounds__(256)
__global__ void scan_prefix(const float* __restrict__ A_log, const float* __restrict__ Ssum,
                            float* __restrict__ hend)
{
    int tid = blockIdx.x * 256 + threadIdx.x;   // 2*DI*16 = 65536
    int n = tid & 15;
    int d = (tid >> 4) & (DI - 1);
    int b = tid >> 15;
    float a = -__expf(A_log[d * 16 + n]);

    size_t row = (size_t)b * NCH_ * DI + d;
    float Sc = Ssum[row];
    float E  = hend[row * 16 + n];
    float h = 0.f;
    for (int c = 0; c < NCH_; ++c) {
        size_t nrow = row + DI;
        float Sn = 0.f, En = 0.f;
        if (c + 1 < NCH_) { Sn = Ssum[nrow]; En = hend[nrow * 16 + n]; }
        float P = __expf(a * Sc);
        hend[row * 16 + n] = h;      // becomes hinit for chunk c
        h  = fmaf(P, h, E);
        Sc = Sn; E = En; row = nrow;
    }
}

template<int NCH_>
__launch_bounds__(256)
__global__ void scan_part2(const bf16* __restrict__ dt, const bf16* __restrict__ xc,
                           const float* __restrict__ xdbl, const bf16* __restrict__ xz,
                           const float* __restrict__ hinit, const float* __restrict__ A_log,
                           const float* __restrict__ Dp, bf16* __restrict__ Y)
{
    constexpr int CLEN_ = LSEQ / NCH_;
    constexpr int LOGN  = (NCH_ == 64) ? 6 : 5;
    int G = blockIdx.x * 256 + threadIdx.x;
    int half = G & 1;
    int d = (G >> 1) & (DI - 1);
    int c = (G >> 12) & (NCH_ - 1);
    int b = G >> (12 + LOGN);
    int n0 = half * 8;

    floatx4 al0 = *(const floatx4*)(A_log + d * 16 + n0);
    floatx4 al1 = *(const floatx4*)(A_log + d * 16 + n0 + 4);
    float a[8];
#pragma unroll
    for (int j = 0; j < 4; ++j) { a[j] = -__expf(al0[j]); a[j + 4] = -__expf(al1[j]); }
    float Dd = Dp[d];

    size_t cid = (size_t)(b * NCH_ + c) * DI + d;
    const float* hi = hinit + cid * 16 + n0;
    floatx4 h0 = *(const floatx4*)hi;
    floatx4 h1 = *(const floatx4*)(hi + 4);
    float h[8] = {h0[0], h0[1], h0[2], h0[3], h1[0], h1[1], h1[2], h1[3]};

    const bf16*  dt_p = dt   + (size_t)b * LSEQ * DI + d;
    const bf16*  xc_p = xc   + (size_t)b * LSEQ * DI + d;
    const float* xb_p = xdbl + (size_t)b * LSEQ * 128 + 64 + n0;   // B slice
    const float* xcc_p= xdbl + (size_t)b * LSEQ * 128 + 80 + n0;   // C slice
    const bf16*  z_p  = xz   + (size_t)b * LSEQ * 4096 + DI + d;
    bf16* y_p = Y + (size_t)b * LSEQ * DI + d;

    const int t0 = c * CLEN_;
#pragma unroll 4
    for (int t = t0; t < t0 + CLEN_; ++t) {
        float dtv = to_f(dt_p[(size_t)t * DI]);
        float xv  = to_f(xc_p[(size_t)t * DI]);
        float zv  = to_f(z_p[(size_t)t * 4096]);
        floatx4 B0 = *(const floatx4*)(xb_p  + (size_t)t * 128);
        floatx4 B1 = *(const floatx4*)(xb_p  + (size_t)t * 128 + 4);
        floatx4 C0 = *(const floatx4*)(xcc_p + (size_t)t * 128);
        floatx4 C1 = *(const floatx4*)(xcc_p + (size_t)t * 128 + 4);
        float dx = dtv * xv;
        float p = 0.f;
#pragma unroll
        for (int j = 0; j < 4; ++j) {
            h[j]     = fmaf(__expf(dtv * a[j]),     h[j],     dx * B0[j]);
            p = fmaf(h[j], C0[j], p);
            h[j + 4] = fmaf(__expf(dtv * a[j + 4]), h[j + 4], dx * B1[j]);
            p = fmaf(h[j + 4], C1[j], p);
        }
        p += __shfl_xor(p, 1);      // combine the two 8-state halves
        if (half == 0) {
            float pp = p + Dd * xv;
            float sz = zv / (1.f + __expf(-zv));
            y_p[(size_t)t * DI] = f2bf(pp * sz);
        }
    }
}

// ---------------------------------------------------------------------------
extern "C" void kernel_launch(void* const* d_in, const int* in_sizes, int n_in,
                              void* d_out, int out_size, void* d_ws, size_t ws_size,
                              hipStream_t stream)
{
    const float* x       = (const float*)d_in[0];
    const float* in_proj = (const float*)d_in[1];
    const float* conv_w  = (const float*)d_in[2];
    const float* conv_b  = (const float*)d_in[3];
    const float* x_proj  = (const float*)d_in[4];
    const float* dt_w    = (const float*)d_in[5];
    const float* dt_b    = (const float*)d_in[6];
    const float* A_log   = (const float*)d_in[7];
    const float* Dp      = (const float*)d_in[8];
    const float* out_w   = (const float*)d_in[9];
    const float* ln1g    = (const float*)d_in[10];
    const float* ln1b    = (const float*)d_in[11];
    const float* ln2g    = (const float*)d_in[12];
    const float* ln2b    = (const float*)d_in[13];
    const float* fw1     = (const float*)d_in[14];
    const float* fb1     = (const float*)d_in[15];
    const float* fw2     = (const float*)d_in[16];
    const float* fb2     = (const float*)d_in[17];
    float* out = (float*)d_out;

    // Base workspace layout (lifetime-aliased):
    //  @0    4MB   h1 / Ssum (<=1MB)
    //  @4    16MB  xz -> Pout -> f1
    //  @20   8MB   xc (-> Y in-place)   | at ffn2: Pf @20..36
    //  @28   1MB   xdf
    //  @29   8MB   dtb                  | step5: Pp fp32 partials @29..45
    //  @37   hend (roomy NCH=64: 16MB @37..53, ipB dead by then) -> x2 @37..45
    //  @45   0.5MB Wpad
    // Roomy (ws >= 74MB): bf16 weights ipB@46 owB@54 fw1B@58 fw2B@66.
    char* w = (char*)d_ws;
    bf16*  h1   = (bf16*)(w);
    bf16*  xz   = (bf16*)(w + (4u  << 20));
    bf16*  xc   = (bf16*)(w + (20u << 20));
    float* xdf  = (float*)(w + (28u << 20));
    bf16*  dtb  = (bf16*)(w + (29u << 20));
    float* Pp   = (float*)(w + (29u << 20));   // 16MB fp32 partials (xproj)
    float* hend = (float*)(w + (37u << 20));
    float* x2   = (float*)(w + (37u << 20));
    bf16*  Wpad = (bf16*)(w + (45u << 20));
    float* Ssum = (float*)(w);
    bf16*  Pout = (bf16*)(w + (4u  << 20));    // 16MB bf16 partials (outproj)
    bf16*  Yb = xc;
    bf16*  f1 = xz;

    const bool roomy = ws_size >= ((size_t)74 << 20);

    if (roomy) {
        bf16* ipB  = (bf16*)(w + (46u << 20));   // 8MB
        bf16* owB  = (bf16*)(w + (54u << 20));   // 4MB
        bf16* fw1B = (bf16*)(w + (58u << 20));   // 8MB
        bf16* fw2B = (bf16*)(w + (66u << 20));   // 8MB
        bf16* Pf   = (bf16*)(w + (20u << 20));   // 16MB (xc/xdf/dtb dead at ffn2)

        cvtw5<<<dim3(7296), dim3(256), 0, stream>>>(in_proj, ipB, out_w, owB,
                                                    fw1, fw1B, fw2, fw2B, x_proj, Wpad);
        ln_kernel<<<dim3(T_TOK), dim3(256), 0, stream>>>(x, ln1g, ln1b, h1);
        g_inproj<<<dim3(16, 32), dim3(256), 0, stream>>>(h1, ipB, xz);
        conv_silu<<<dim3(T_TOK * DI / 8 / 256), dim3(256), 0, stream>>>(xz, conv_w, conv_b, xc);
        g_xproj<<<dim3(16, 1, 16), dim3(256), 0, stream>>>(xc, Wpad, Pp);
        reduce16<<<dim3(256), dim3(256), 0, stream>>>(Pp, xdf);
        gemm_dt64<<<dim3(64, 16), dim3(256), 0, stream>>>(xdf, dt_w, dt_b, dtb);
        scan_part1<64><<<dim3(2048), dim3(256), 0, stream>>>(dtb, xc, xdf, A_log, Ssum, hend);
        scan_prefix<64><<<dim3(256), dim3(256), 0, stream>>>(A_log, Ssum, hend);
        scan_part2<64><<<dim3(2048), dim3(256), 0, stream>>>(dtb, xc, xdf, xz, hend, A_log, Dp, Yb);
        g_outproj<<<dim3(16, 8, 4), dim3(256), 0, stream>>>(Yb, owB, Pout);
        red4_ln<<<dim3(T_TOK), dim3(256), 0, stream>>>(Pout, x, ln2g, ln2b, x2, h1);
        g_ffn1<<<dim3(16, 32), dim3(256), 0, stream>>>(h1, fw1B, f1, fb1);
        g_ffn2_4<<<dim3(16, 8, 4), dim3(256), 0, stream>>>(f1, fw2B, Pf);
        red_bias_resid<4><<<dim3(1024), dim3(256), 0, stream>>>(Pf, fb2, x2, out);
    } else {
        bf16* ipB  = (bf16*)(w + (20u << 20));   // pre-conv, xc region free
        bf16* owB  = (bf16*)(w);                 // post-prefix, Ssum dead
        bf16* fw1B = (bf16*)(w + (29u << 20));   // post-scan, dtb dead
        bf16* fw2B = (bf16*)(w + (20u << 20));   // post-outproj, Y dead
        bf16* Pf   = (bf16*)(w + (28u << 20));   // 8MB, KS=2 (xdf/fw1B dead)

        cvtw<<<dim3(2048), dim3(256), 0, stream>>>(in_proj, ipB);
        ln_kernel<<<dim3(T_TOK), dim3(256), 0, stream>>>(x, ln1g, ln1b, h1);
        g_inproj<<<dim3(16, 32), dim3(256), 0, stream>>>(h1, ipB, xz);
        conv_silu<<<dim3(T_TOK * DI / 8 / 256), dim3(256), 0, stream>>>(xz, conv_w, conv_b, xc);
        padw_kernel<<<dim3(128 * 2048 / 256), dim3(256), 0, stream>>>(x_proj, Wpad);
        g_xproj<<<dim3(16, 1, 16), dim3(256), 0, stream>>>(xc, Wpad, Pp);
        reduce16<<<dim3(256), dim3(256), 0, stream>>>(Pp, xdf);
        gemm_dt64<<<dim3(64, 16), dim3(256), 0, stream>>>(xdf, dt_w, dt_b, dtb);
        scan_part1<32><<<dim3(1024), dim3(256), 0, stream>>>(dtb, xc, xdf, A_log, Ssum, hend);
        scan_prefix<32><<<dim3(256), dim3(256), 0, stream>>>(A_log, Ssum, hend);
        cvtw<<<dim3(1024), dim3(256), 0, stream>>>(out_w, owB);
        scan_part2<32><<<dim3(1024), dim3(256), 0, stream>>>(dtb, xc, xdf, xz, hend, A_log, Dp, Yb);
        g_outproj<<<dim3(16, 8, 4), dim3(256), 0, stream>>>(Yb, owB, Pout);
        cvtw<<<dim3(2048), dim3(256), 0, stream>>>(fw1, fw1B);
        red4_ln<<<dim3(T_TOK), dim3(256), 0, stream>>>(Pout, x, ln2g, ln2b, x2, h1);
        g_ffn1<<<dim3(16, 32), dim3(256), 0, stream>>>(h1, fw1B, f1, fb1);
        cvtw<<<dim3(2048), dim3(256), 0, stream>>>(fw2, fw2B);
        g_ffn2_2<<<dim3(16, 8, 2), dim3(256), 0, stream>>>(f1, fw2B, Pf);
        red_bias_resid<2><<<dim3(1024), dim3(256), 0, stream>>>(Pf, fb2, x2, out);
    }
}

// Round 7
// 352.694 us; speedup vs baseline: 1.0695x; 1.0695x over previous
//
#include <hip/hip_runtime.h>
#include <hip/hip_bf16.h>

#define T_TOK 2048   // BATCH*SEQLEN
#define LSEQ  1024
#define DM    1024
#define DI    2048
#define LDW2  72     // LDS row stride for K=64 dt gemm

using bf16 = __hip_bfloat16;
typedef __attribute__((ext_vector_type(8))) short short8;
typedef __attribute__((ext_vector_type(4))) short short4b;
typedef __attribute__((ext_vector_type(4))) float floatx4;

__device__ inline float to_f(float v) { return v; }
__device__ inline float to_f(bf16 v) { return __bfloat162float(v); }
__device__ inline bf16  f2bf(float v) { return __float2bfloat16(v); }
__device__ inline float bf2f(short s) { return __bfloat162float(__builtin_bit_cast(bf16, s)); }

// load 8 contiguous elements as bf16 bit-pattern (converting if fp32 source)
__device__ inline short8 ld8(const bf16* p) { return *(const short8*)p; }
__device__ inline short8 ld8(const float* p) {
    floatx4 f0 = *(const floatx4*)p;
    floatx4 f1 = *(const floatx4*)(p + 4);
    short8 r;
#pragma unroll
    for (int i = 0; i < 4; ++i) {
        r[i]     = __builtin_bit_cast(short, __float2bfloat16(f0[i]));
        r[i + 4] = __builtin_bit_cast(short, __float2bfloat16(f1[i]));
    }
    return r;
}

// async global->LDS, 16B per lane (dest = wave-uniform base + lane*16)
__device__ __forceinline__ void gload16(const void* g, void* l) {
    __builtin_amdgcn_global_load_lds(
        (const __attribute__((address_space(1))) unsigned int*)g,
        (__attribute__((address_space(3))) unsigned int*)l, 16, 0, 0);
}

// Linear [row][32] bf16 tile with XOR involution on the 16B slot index:
// col ^= ((row>>1)&3)<<3.  Combined with row*16-dword stride (parity from
// row bit0), each quarter-wave of a ds_read_b128 hits each 4-bank set with
// exactly 2 lanes -> conflict-free.  Same XOR applied to the GLOBAL source
// column during staging (linear dest, pre-swizzled source).
__device__ __forceinline__ int swz32(int row, int col) {
    return row * 32 + (col ^ (((row >> 1) & 3) << 3));
}

// ---------------------------------------------------------------------------
// GEMM core: C[M,N] = A[M,K] @ W[N,K]^T, both bf16. 128x128 tile, BK=32,
// m97-structure (single LDS buffer, __syncthreads, global_load_lds(16B),
// compiler-scheduled waitcnts — R5's explicit dbuf+sched_barrier REGRESSED,
// m141-style). 512 threads = 8 waves (wave tile 64x32, acc 4x2): same tiles,
// grids and traffic as the 4-wave version but 2x waves/CU (16 at 2 blk/CU)
// for latency hiding — the R3/R4 counters showed latency-bound (occ 18%,
// MfmaUtil 9%, all throughput ceilings slack).
// EPI: 0 bf16 | 2 bf16 softplus(c+bias) | 4 bf16 relu(c+bias)
//      7 fp32 partial @ +bz*zstr | 8 bf16 partial @ +bz*zstr
// ---------------------------------------------------------------------------
template<int EPI, int KS>
__device__ __forceinline__ void gemm_core(
    const bf16* __restrict__ A, int lda,
    const bf16* __restrict__ W, int K,
    float* __restrict__ outF, bf16* __restrict__ outB, int ldc,
    const float* __restrict__ bias, size_t zstr)
{
    __shared__ __align__(16) bf16 sA[128 * 32];
    __shared__ __align__(16) bf16 sW[128 * 32];
    const int tid  = threadIdx.x;              // 0..511
    const int lane = tid & 63, wid = tid >> 6; // 8 waves

    // bijective chunked XCD swizzle (all grids have nwg % 8 == 0)
    const int nwg = gridDim.x * gridDim.y * gridDim.z;
    const int lin = blockIdx.x + gridDim.x * (blockIdx.y + gridDim.y * blockIdx.z);
    const int sid = (lin & 7) * (nwg >> 3) + (lin >> 3);
    const int bx  = sid % gridDim.x;
    const int byz = sid / gridDim.x;
    const int by  = byz % gridDim.y;
    const int bz  = byz / gridDim.y;

    const int m0 = bx * 128, n0 = by * 128;
    const int wm = (wid >> 2) * 64;            // 2 wave-rows
    const int wn = (wid & 3) * 32;             // 4 wave-cols
    const int lr = lane & 15, lh = lane >> 4;

    // staging: thread covers one 16B chunk of one A row and one W row
    const int r0  = tid >> 2;                  // 0..127
    const int gc0 = ((tid & 3) * 8) ^ (((r0 >> 1) & 3) << 3);

    const int kBeg = bz * (K / KS);
    const int kEnd = kBeg + K / KS;

    const bf16* Ag = A + (size_t)(m0 + r0) * lda + kBeg + gc0;
    const bf16* Wg = W + (size_t)(n0 + r0) * K   + kBeg + gc0;

    // wave-uniform LDS dests: wave w stages rows [w*16, w*16+16)
    bf16* sAd = sA + wid * 512;
    bf16* sWd = sW + wid * 512;

    floatx4 acc[4][2];
#pragma unroll
    for (int i = 0; i < 4; ++i)
#pragma unroll
        for (int j = 0; j < 2; ++j) acc[i][j] = (floatx4){0.f, 0.f, 0.f, 0.f};

    for (int k0 = kBeg; k0 < kEnd; k0 += 32) {
        __syncthreads();                 // prev iter's LDS reads complete
        gload16(Ag, sAd);
        gload16(Wg, sWd);
        Ag += 32; Wg += 32;
        __syncthreads();                 // compiler drains vmcnt before barrier

        short8 af[4], wf[2];
#pragma unroll
        for (int i = 0; i < 4; ++i)
            af[i] = *(const short8*)(sA + swz32(wm + i * 16 + lr, lh * 8));
#pragma unroll
        for (int j = 0; j < 2; ++j)
            wf[j] = *(const short8*)(sW + swz32(wn + j * 16 + lr, lh * 8));
#pragma unroll
        for (int i = 0; i < 4; ++i)
#pragma unroll
            for (int j = 0; j < 2; ++j)
                acc[i][j] = __builtin_amdgcn_mfma_f32_16x16x32_bf16(af[i], wf[j], acc[i][j], 0, 0, 0);
    }

    // epilogue: C/D layout col=lane&15, row=(lane>>4)*4+reg
#pragma unroll
    for (int i = 0; i < 4; ++i) {
#pragma unroll
        for (int j = 0; j < 2; ++j) {
#pragma unroll
            for (int r = 0; r < 4; ++r) {
                int row = m0 + wm + i * 16 + lh * 4 + r;
                int col = n0 + wn + j * 16 + lr;
                size_t off = (size_t)row * ldc + col;
                float c = acc[i][j][r];
                if (EPI == 0) {
                    outB[off] = f2bf(c);
                } else if (EPI == 2) {
                    float v = c + bias[col];
                    outB[off] = f2bf((v > 15.f) ? v : log1pf(__expf(v)));
                } else if (EPI == 4) {
                    float v = c + bias[col];
                    outB[off] = f2bf(v > 0.f ? v : 0.f);
                } else if (EPI == 7) {
                    outF[off + (size_t)bz * zstr] = c;
                } else if (EPI == 8) {
                    outB[off + (size_t)bz * zstr] = f2bf(c);
                }
            }
        }
    }
}

// named wrappers (distinct symbols -> distinct rocprof rows)
__launch_bounds__(512, 4)
__global__ void g_inproj(const bf16* __restrict__ A, const bf16* __restrict__ W,
                         bf16* __restrict__ outB)
{ gemm_core<0, 1>(A, DM, W, DM, nullptr, outB, 4096, nullptr, 0); }

__launch_bounds__(512, 4)
__global__ void g_xproj(const bf16* __restrict__ A, const bf16* __restrict__ W,
                        float* __restrict__ outF)
{ gemm_core<7, 16>(A, DI, W, DI, outF, nullptr, 128, nullptr, (size_t)T_TOK * 128); }

__launch_bounds__(512, 4)
__global__ void g_outproj(const bf16* __restrict__ A, const bf16* __restrict__ W,
                          bf16* __restrict__ outB)
{ gemm_core<8, 4>(A, DI, W, DI, nullptr, outB, DM, nullptr, (size_t)T_TOK * DM); }

__launch_bounds__(512, 4)
__global__ void g_ffn1(const bf16* __restrict__ A, const bf16* __restrict__ W,
                       bf16* __restrict__ outB, const float* __restrict__ bias)
{ gemm_core<4, 1>(A, DM, W, DM, nullptr, outB, 4096, bias, 0); }

__launch_bounds__(512, 4)
__global__ void g_ffn2_4(const bf16* __restrict__ A, const bf16* __restrict__ W,
                         bf16* __restrict__ outB)
{ gemm_core<8, 4>(A, 4096, W, 4096, nullptr, outB, DM, nullptr, (size_t)T_TOK * DM); }

__launch_bounds__(512, 4)
__global__ void g_ffn2_2(const bf16* __restrict__ A, const bf16* __restrict__ W,
                         bf16* __restrict__ outB)
{ gemm_core<8, 2>(A, 4096, W, 4096, nullptr, outB, DM, nullptr, (size_t)T_TOK * DM); }

// fp32 -> bf16 weight conversion (8 elems/thread)
__launch_bounds__(256)
__global__ void cvtw(const float* __restrict__ src, bf16* __restrict__ dst)
{
    size_t i = ((size_t)blockIdx.x * 256 + threadIdx.x) * 8;
    *(short8*)(dst + i) = ld8(src + i);
}

// fused 4-array weight conversion + x_proj pad (roomy mode; one launch)
__launch_bounds__(256)
__global__ void cvtw5(const float* __restrict__ s0, bf16* __restrict__ d0,
                      const float* __restrict__ s1, bf16* __restrict__ d1,
                      const float* __restrict__ s2, bf16* __restrict__ d2,
                      const float* __restrict__ s3, bf16* __restrict__ d3,
                      const float* __restrict__ s4, bf16* __restrict__ d4)
{
    constexpr size_t N0 = (size_t)2 * DI * DM;   // in_proj
    constexpr size_t N1 = (size_t)DM * DI;       // out_w
    constexpr size_t N2 = (size_t)4 * DM * DM;   // fw1
    constexpr size_t N3 = (size_t)DM * 4 * DM;   // fw2
    size_t i = ((size_t)blockIdx.x * 256 + threadIdx.x) * 8;
    if (i < N0) { *(short8*)(d0 + i) = ld8(s0 + i); return; }
    i -= N0;
    if (i < N1) { *(short8*)(d1 + i) = ld8(s1 + i); return; }
    i -= N1;
    if (i < N2) { *(short8*)(d2 + i) = ld8(s2 + i); return; }
    i -= N2;
    if (i < N3) { *(short8*)(d3 + i) = ld8(s3 + i); return; }
    i -= N3;
    // x_proj pad: [96,2048] fp32 -> [128,2048] bf16, zero rows >= 96
    int row = (int)(i >> 11);
    if (row < 96) { *(short8*)(d4 + i) = ld8(s4 + i); }
    else { *(short8*)(d4 + i) = (short8){0,0,0,0,0,0,0,0}; }
}

// ---------------------------------------------------------------------------
// dt GEMM, specialized: dtb = softplus(xdf[:, :64] @ dt_w^T + dt_b)
// M=2048, N=2048, K=64. BM=32, BN=128 -> grid (64,16)=1024 blocks.
// ---------------------------------------------------------------------------
__launch_bounds__(256)
__global__ void gemm_dt64(const float* __restrict__ A,   // xdf [2048,128]
                          const float* __restrict__ W,   // dt_w [2048,64]
                          const float* __restrict__ bias,
                          bf16* __restrict__ outB)       // dtb [2048,2048]
{
    __shared__ __align__(16) bf16 sA[32 * LDW2];
    __shared__ __align__(16) bf16 sW[128 * LDW2];
    const int tid = threadIdx.x;
    const int lane = tid & 63, w = tid >> 6;
    const int m0 = blockIdx.x * 32, n0 = blockIdx.y * 128;

    {   // stage A: 32 rows x 64 cols (1 ld8/thread)
        int ar = tid >> 3, ac = (tid & 7) * 8;
        *(short8*)(sA + ar * LDW2 + ac) = ld8(A + (size_t)(m0 + ar) * 128 + ac);
        // stage W: 128 rows x 64 cols (4 ld8/thread)
        int wr = tid >> 1, wc = (tid & 1) * 32;
        const float* wp = W + (size_t)(n0 + wr) * 64 + wc;
        *(short8*)(sW + wr * LDW2 + wc)      = ld8(wp);
        *(short8*)(sW + wr * LDW2 + wc + 8)  = ld8(wp + 8);
        *(short8*)(sW + wr * LDW2 + wc + 16) = ld8(wp + 16);
        *(short8*)(sW + wr * LDW2 + wc + 24) = ld8(wp + 24);
    }
    __syncthreads();

    const int lr = lane & 15, lh = lane >> 4;
    floatx4 acc[2][2];
#pragma unroll
    for (int i = 0; i < 2; ++i)
#pragma unroll
        for (int j = 0; j < 2; ++j) acc[i][j] = (floatx4){0.f, 0.f, 0.f, 0.f};

#pragma unroll
    for (int kk = 0; kk < 2; ++kk) {
        short8 af[2], wf[2];
#pragma unroll
        for (int i = 0; i < 2; ++i)
            af[i] = *(const short8*)(sA + (i * 16 + lr) * LDW2 + kk * 32 + lh * 8);
#pragma unroll
        for (int j = 0; j < 2; ++j)
            wf[j] = *(const short8*)(sW + (w * 32 + j * 16 + lr) * LDW2 + kk * 32 + lh * 8);
#pragma unroll
        for (int i = 0; i < 2; ++i)
#pragma unroll
            for (int j = 0; j < 2; ++j)
                acc[i][j] = __builtin_amdgcn_mfma_f32_16x16x32_bf16(af[i], wf[j], acc[i][j], 0, 0, 0);
    }

#pragma unroll
    for (int i = 0; i < 2; ++i) {
#pragma unroll
        for (int j = 0; j < 2; ++j) {
#pragma unroll
            for (int r = 0; r < 4; ++r) {
                int row = m0 + i * 16 + lh * 4 + r;
                int col = n0 + w * 32 + j * 16 + lr;
                float v = acc[i][j][r] + bias[col];
                outB[(size_t)row * DI + col] = f2bf((v > 15.f) ? v : log1pf(__expf(v)));
            }
        }
    }
}

// sum 16 split-K fp32 partial slices -> xdf
__launch_bounds__(256)
__global__ void reduce16(const float* __restrict__ P, float* __restrict__ out)
{
    int i = blockIdx.x * 256 + threadIdx.x;            // float4 idx, 65536 total
    const floatx4* P4 = (const floatx4*)P;
    floatx4 s = (floatx4){0.f, 0.f, 0.f, 0.f};
#pragma unroll
    for (int z = 0; z < 16; ++z) s += P4[(size_t)z * 65536 + i];
    ((floatx4*)out)[i] = s;
}

// Fused: x2 = x + sum_{z<4} P[z] ; h1 = LayerNorm(x2; g,b).  Block per token.
__launch_bounds__(256)
__global__ void red4_ln(const bf16* __restrict__ P, const float* __restrict__ x,
                        const float* __restrict__ g, const float* __restrict__ bb,
                        float* __restrict__ x2, bf16* __restrict__ h1)
{
    int t = blockIdx.x, tid = threadIdx.x;
    size_t rowoff = (size_t)t * DM + tid * 4;
    floatx4 xv = *(const floatx4*)(x + rowoff);
    float v[4];
#pragma unroll
    for (int i = 0; i < 4; ++i) v[i] = xv[i];
#pragma unroll
    for (int z = 0; z < 4; ++z) {
        short4b p = *(const short4b*)(P + (size_t)z * T_TOK * DM + rowoff);
#pragma unroll
        for (int i = 0; i < 4; ++i) v[i] += bf2f(p[i]);
    }
    *(floatx4*)(x2 + rowoff) = (floatx4){v[0], v[1], v[2], v[3]};
    float s = v[0] + v[1] + v[2] + v[3];
    float ss = v[0]*v[0] + v[1]*v[1] + v[2]*v[2] + v[3]*v[3];
#pragma unroll
    for (int o = 1; o < 64; o <<= 1) { s += __shfl_xor(s, o); ss += __shfl_xor(ss, o); }
    __shared__ float red[8];
    int lane = tid & 63, wid = tid >> 6;
    if (lane == 0) { red[wid] = s; red[wid + 4] = ss; }
    __syncthreads();
    s  = red[0] + red[1] + red[2] + red[3];
    ss = red[4] + red[5] + red[6] + red[7];
    float mu  = s * (1.f / DM);
    float var = ss * (1.f / DM) - mu * mu;
    float rs  = rsqrtf(var + 1e-5f);
    int c = tid * 4;
    short4b o4;
#pragma unroll
    for (int i = 0; i < 4; ++i)
        o4[i] = __builtin_bit_cast(short, f2bf((v[i] - mu) * rs * g[c + i] + bb[c + i]));
    *(short4b*)(h1 + rowoff) = o4;
}

// out = bias[col] + resid + sum_{z<Z} P[z]
template<int Z>
__launch_bounds__(256)
__global__ void red_bias_resid(const bf16* __restrict__ P, const float* __restrict__ bias,
                               const float* __restrict__ resid, float* __restrict__ out)
{
    size_t base = ((size_t)blockIdx.x * 256 + threadIdx.x) * 8;
    int c = (int)(base & (DM - 1));
    floatx4 b0 = *(const floatx4*)(bias + c);
    floatx4 b1 = *(const floatx4*)(bias + c + 4);
    floatx4 x0 = *(const floatx4*)(resid + base);
    floatx4 x1 = *(const floatx4*)(resid + base + 4);
    float s[8];
#pragma unroll
    for (int j = 0; j < 4; ++j) { s[j] = x0[j] + b0[j]; s[j + 4] = x1[j] + b1[j]; }
#pragma unroll
    for (int z = 0; z < Z; ++z) {
        short8 p = *(const short8*)(P + (size_t)z * T_TOK * DM + base);
#pragma unroll
        for (int j = 0; j < 8; ++j) s[j] += bf2f(p[j]);
    }
    *(floatx4*)(out + base)     = (floatx4){s[0], s[1], s[2], s[3]};
    *(floatx4*)(out + base + 4) = (floatx4){s[4], s[5], s[6], s[7]};
}

// ---------------------------------------------------------------------------
// LayerNorm over 1024 dims (fp32 in/params), one block per token, bf16 out
// ---------------------------------------------------------------------------
__launch_bounds__(256)
__global__ void ln_kernel(const float* __restrict__ x, const float* __restrict__ g,
                          const float* __restrict__ bb, bf16* __restrict__ out)
{
    int t = blockIdx.x, tid = threadIdx.x;
    const float* xr = x + (size_t)t * DM;
    float v[4], s = 0.f, ss = 0.f;
#pragma unroll
    for (int i = 0; i < 4; ++i) {
        v[i] = xr[tid + i * 256];
        s += v[i]; ss += v[i] * v[i];
    }
#pragma unroll
    for (int o = 1; o < 64; o <<= 1) { s += __shfl_xor(s, o); ss += __shfl_xor(ss, o); }
    __shared__ float red[8];
    int lane = tid & 63, wid = tid >> 6;
    if (lane == 0) { red[wid] = s; red[wid + 4] = ss; }
    __syncthreads();
    s  = red[0] + red[1] + red[2] + red[3];
    ss = red[4] + red[5] + red[6] + red[7];
    float mu  = s * (1.f / DM);
    float var = ss * (1.f / DM) - mu * mu;
    float rs  = rsqrtf(var + 1e-5f);
#pragma unroll
    for (int i = 0; i < 4; ++i) {
        int c = tid + i * 256;
        out[(size_t)t * DM + c] = f2bf((v[i] - mu) * rs * g[c] + bb[c]);
    }
}

// ---------------------------------------------------------------------------
// depthwise causal conv (k=4, fp32 weights) + bias + SiLU -> bf16.
// Vectorized: 8 consecutive d per thread (4x short8 loads, 1x short8 store).
// ---------------------------------------------------------------------------
__launch_bounds__(256)
__global__ void conv_silu(const bf16* __restrict__ xz, const float* __restrict__ cw,
                          const float* __restrict__ cb, bf16* __restrict__ xcb)
{
    int idx = (blockIdx.x * 256 + threadIdx.x) * 8;   // T_TOK*DI elems
    int d  = idx & (DI - 1);
    int tk = idx >> 11;
    int t  = tk & (LSEQ - 1);
    const short8 zero = {0, 0, 0, 0, 0, 0, 0, 0};
    short8 x3 = ld8(xz + (size_t)tk * 4096 + d);
    short8 x2 = (t >= 1) ? ld8(xz + (size_t)(tk - 1) * 4096 + d) : zero;
    short8 x1 = (t >= 2) ? ld8(xz + (size_t)(tk - 2) * 4096 + d) : zero;
    short8 x0 = (t >= 3) ? ld8(xz + (size_t)(tk - 3) * 4096 + d) : zero;
    short8 r;
#pragma unroll
    for (int j = 0; j < 8; ++j) {
        floatx4 wv = *(const floatx4*)(cw + (size_t)(d + j) * 4);
        float acc = cb[d + j]
                  + wv[0] * bf2f(x0[j]) + wv[1] * bf2f(x1[j])
                  + wv[2] * bf2f(x2[j]) + wv[3] * bf2f(x3[j]);
        float s = acc / (1.f + __expf(-acc));
        r[j] = __builtin_bit_cast(short, f2bf(s));
    }
    *(short8*)(xcb + idx) = r;
}

// pad x_proj_w fp32 [96,2048] -> bf16 [128,2048] with zero rows (tight mode)
__launch_bounds__(256)
__global__ void padw_kernel(const float* __restrict__ w, bf16* __restrict__ wp)
{
    int idx = blockIdx.x * 256 + threadIdx.x;   // 128*2048
    int row = idx >> 11;
    wp[idx] = (row < 96) ? f2bf(w[idx]) : f2bf(0.f);
}

// ---------------------------------------------------------------------------
// Chunked selective scan, 3 phases, 8 states per thread (2 threads per (b,d)
// chain). Template NCH_: chunk count (roomy=64 for 8 blocks/CU TLP).
// ---------------------------------------------------------------------------
template<int NCH_>
__launch_bounds__(256)
__global__ void scan_part1(const bf16* __restrict__ dt, const bf16* __restrict__ xc,
                           const float* __restrict__ xdbl, const float* __restrict__ A_log,
                           float* __restrict__ Ssum, float* __restrict__ hend)
{
    constexpr int CLEN_ = LSEQ / NCH_;
    constexpr int LOGN  = (NCH_ == 64) ? 6 : 5;
    int G = blockIdx.x * 256 + threadIdx.x;     // 2 * NCH_ * DI * 2
    int half = G & 1;
    int d = (G >> 1) & (DI - 1);
    int c = (G >> 12) & (NCH_ - 1);
    int b = G >> (12 + LOGN);
    int n0 = half * 8;

    floatx4 al0 = *(const floatx4*)(A_log + d * 16 + n0);
    floatx4 al1 = *(const floatx4*)(A_log + d * 16 + n0 + 4);
    float a[8];
#pragma unroll
    for (int j = 0; j < 4; ++j) { a[j] = -__expf(al0[j]); a[j + 4] = -__expf(al1[j]); }

    const bf16*  dt_p = dt   + (size_t)b * LSEQ * DI + d;
    const bf16*  xc_p = xc   + (size_t)b * LSEQ * DI + d;
    const float* xb_p = xdbl + (size_t)b * LSEQ * 128 + 64 + n0;   // B slice

    float h[8];
#pragma unroll
    for (int j = 0; j < 8; ++j) h[j] = 0.f;
    float S = 0.f;

    const int t0 = c * CLEN_;
#pragma unroll 4
    for (int t = t0; t < t0 + CLEN_; ++t) {
        float dtv = to_f(dt_p[(size_t)t * DI]);
        float xv  = to_f(xc_p[(size_t)t * DI]);
        floatx4 B0 = *(const floatx4*)(xb_p + (size_t)t * 128);
        floatx4 B1 = *(const floatx4*)(xb_p + (size_t)t * 128 + 4);
        S += dtv;
        float dx = dtv * xv;
#pragma unroll
        for (int j = 0; j < 4; ++j) {
            h[j]     = fmaf(__expf(dtv * a[j]),     h[j],     dx * B0[j]);
            h[j + 4] = fmaf(__expf(dtv * a[j + 4]), h[j + 4], dx * B1[j]);
        }
    }

    size_t cid = (size_t)(b * NCH_ + c) * DI + d;
    if (half == 0) Ssum[cid] = S;
    float* he = hend + cid * 16 + n0;
    *(floatx4*)he       = (floatx4){h[0], h[1], h[2], h[3]};
    *(floatx4*)(he + 4) = (floatx4){h[4], h[5], h[6], h[7]};
}

template<int NCH_>
__launch_bounds__(256)
__global__ void scan_prefix(const float* __restrict__ A_log, const float* __restrict__ Ssum,
                            float* __restrict__ hend)
{
    int tid = blockIdx.x * 256 + threadIdx.x;   // 2*DI*16 = 65536
    int n = tid & 15;
    int d = (tid >> 4) & (DI - 1);
    int b = tid >> 15;
    float a = -__expf(A_log[d * 16 + n]);

    size_t row = (size_t)b * NCH_ * DI + d;
    float Sc = Ssum[row];
    float E  = hend[row * 16 + n];
    float h = 0.f;
    for (int c = 0; c < NCH_; ++c) {
        size_t nrow = row + DI;
        float Sn = 0.f, En = 0.f;
        if (c + 1 < NCH_) { Sn = Ssum[nrow]; En = hend[nrow * 16 + n]; }
        float P = __expf(a * Sc);
        hend[row * 16 + n] = h;      // becomes hinit for chunk c
        h  = fmaf(P, h, E);
        Sc = Sn; E = En; row = nrow;
    }
}

template<int NCH_>
__launch_bounds__(256)
__global__ void scan_part2(const bf16* __restrict__ dt, const bf16* __restrict__ xc,
                           const float* __restrict__ xdbl, const bf16* __restrict__ xz,
                           const float* __restrict__ hinit, const float* __restrict__ A_log,
                           const float* __restrict__ Dp, bf16* __restrict__ Y)
{
    constexpr int CLEN_ = LSEQ / NCH_;
    constexpr int LOGN  = (NCH_ == 64) ? 6 : 5;
    int G = blockIdx.x * 256 + threadIdx.x;
    int half = G & 1;
    int d = (G >> 1) & (DI - 1);
    int c = (G >> 12) & (NCH_ - 1);
    int b = G >> (12 + LOGN);
    int n0 = half * 8;

    floatx4 al0 = *(const floatx4*)(A_log + d * 16 + n0);
    floatx4 al1 = *(const floatx4*)(A_log + d * 16 + n0 + 4);
    float a[8];
#pragma unroll
    for (int j = 0; j < 4; ++j) { a[j] = -__expf(al0[j]); a[j + 4] = -__expf(al1[j]); }
    float Dd = Dp[d];

    size_t cid = (size_t)(b * NCH_ + c) * DI + d;
    const float* hi = hinit + cid * 16 + n0;
    floatx4 h0 = *(const floatx4*)hi;
    floatx4 h1 = *(const floatx4*)(hi + 4);
    float h[8] = {h0[0], h0[1], h0[2], h0[3], h1[0], h1[1], h1[2], h1[3]};

    const bf16*  dt_p = dt   + (size_t)b * LSEQ * DI + d;
    const bf16*  xc_p = xc   + (size_t)b * LSEQ * DI + d;
    const float* xb_p = xdbl + (size_t)b * LSEQ * 128 + 64 + n0;   // B slice
    const float* xcc_p= xdbl + (size_t)b * LSEQ * 128 + 80 + n0;   // C slice
    const bf16*  z_p  = xz   + (size_t)b * LSEQ * 4096 + DI + d;
    bf16* y_p = Y + (size_t)b * LSEQ * DI + d;

    const int t0 = c * CLEN_;
#pragma unroll 4
    for (int t = t0; t < t0 + CLEN_; ++t) {
        float dtv = to_f(dt_p[(size_t)t * DI]);
        float xv  = to_f(xc_p[(size_t)t * DI]);
        float zv  = to_f(z_p[(size_t)t * 4096]);
        floatx4 B0 = *(const floatx4*)(xb_p  + (size_t)t * 128);
        floatx4 B1 = *(const floatx4*)(xb_p  + (size_t)t * 128 + 4);
        floatx4 C0 = *(const floatx4*)(xcc_p + (size_t)t * 128);
        floatx4 C1 = *(const floatx4*)(xcc_p + (size_t)t * 128 + 4);
        float dx = dtv * xv;
        float p = 0.f;
#pragma unroll
        for (int j = 0; j < 4; ++j) {
            h[j]     = fmaf(__expf(dtv * a[j]),     h[j],     dx * B0[j]);
            p = fmaf(h[j], C0[j], p);
            h[j + 4] = fmaf(__expf(dtv * a[j + 4]), h[j + 4], dx * B1[j]);
            p = fmaf(h[j + 4], C1[j], p);
        }
        p += __shfl_xor(p, 1);      // combine the two 8-state halves
        if (half == 0) {
            float pp = p + Dd * xv;
            float sz = zv / (1.f + __expf(-zv));
            y_p[(size_t)t * DI] = f2bf(pp * sz);
        }
    }
}

// ---------------------------------------------------------------------------
extern "C" void kernel_launch(void* const* d_in, const int* in_sizes, int n_in,
                              void* d_out, int out_size, void* d_ws, size_t ws_size,
                              hipStream_t stream)
{
    const float* x       = (const float*)d_in[0];
    const float* in_proj = (const float*)d_in[1];
    const float* conv_w  = (const float*)d_in[2];
    const float* conv_b  = (const float*)d_in[3];
    const float* x_proj  = (const float*)d_in[4];
    const float* dt_w    = (const float*)d_in[5];
    const float* dt_b    = (const float*)d_in[6];
    const float* A_log   = (const float*)d_in[7];
    const float* Dp      = (const float*)d_in[8];
    const float* out_w   = (const float*)d_in[9];
    const float* ln1g    = (const float*)d_in[10];
    const float* ln1b    = (const float*)d_in[11];
    const float* ln2g    = (const float*)d_in[12];
    const float* ln2b    = (const float*)d_in[13];
    const float* fw1     = (const float*)d_in[14];
    const float* fb1     = (const float*)d_in[15];
    const float* fw2     = (const float*)d_in[16];
    const float* fb2     = (const float*)d_in[17];
    float* out = (float*)d_out;

    // Base workspace layout (lifetime-aliased):
    //  @0    4MB   h1 / Ssum (<=1MB)
    //  @4    16MB  xz -> Pout -> f1
    //  @20   8MB   xc (-> Y in-place)   | at ffn2: Pf @20..36
    //  @28   1MB   xdf
    //  @29   8MB   dtb                  | step5: Pp fp32 partials @29..45
    //  @37   hend (roomy NCH=64: 16MB @37..53, ipB dead by then) -> x2 @37..45
    //  @45   0.5MB Wpad
    // Roomy (ws >= 74MB): bf16 weights ipB@46 owB@54 fw1B@58 fw2B@66.
    char* w = (char*)d_ws;
    bf16*  h1   = (bf16*)(w);
    bf16*  xz   = (bf16*)(w + (4u  << 20));
    bf16*  xc   = (bf16*)(w + (20u << 20));
    float* xdf  = (float*)(w + (28u << 20));
    bf16*  dtb  = (bf16*)(w + (29u << 20));
    float* Pp   = (float*)(w + (29u << 20));   // 16MB fp32 partials (xproj)
    float* hend = (float*)(w + (37u << 20));
    float* x2   = (float*)(w + (37u << 20));
    bf16*  Wpad = (bf16*)(w + (45u << 20));
    float* Ssum = (float*)(w);
    bf16*  Pout = (bf16*)(w + (4u  << 20));    // 16MB bf16 partials (outproj)
    bf16*  Yb = xc;
    bf16*  f1 = xz;

    const bool roomy = ws_size >= ((size_t)74 << 20);

    if (roomy) {
        bf16* ipB  = (bf16*)(w + (46u << 20));   // 8MB
        bf16* owB  = (bf16*)(w + (54u << 20));   // 4MB
        bf16* fw1B = (bf16*)(w + (58u << 20));   // 8MB
        bf16* fw2B = (bf16*)(w + (66u << 20));   // 8MB
        bf16* Pf   = (bf16*)(w + (20u << 20));   // 16MB (xc/xdf/dtb dead at ffn2)

        cvtw5<<<dim3(7296), dim3(256), 0, stream>>>(in_proj, ipB, out_w, owB,
                                                    fw1, fw1B, fw2, fw2B, x_proj, Wpad);
        ln_kernel<<<dim3(T_TOK), dim3(256), 0, stream>>>(x, ln1g, ln1b, h1);
        g_inproj<<<dim3(16, 32), dim3(512), 0, stream>>>(h1, ipB, xz);
        conv_silu<<<dim3(T_TOK * DI / 8 / 256), dim3(256), 0, stream>>>(xz, conv_w, conv_b, xc);
        g_xproj<<<dim3(16, 1, 16), dim3(512), 0, stream>>>(xc, Wpad, Pp);
        reduce16<<<dim3(256), dim3(256), 0, stream>>>(Pp, xdf);
        gemm_dt64<<<dim3(64, 16), dim3(256), 0, stream>>>(xdf, dt_w, dt_b, dtb);
        scan_part1<64><<<dim3(2048), dim3(256), 0, stream>>>(dtb, xc, xdf, A_log, Ssum, hend);
        scan_prefix<64><<<dim3(256), dim3(256), 0, stream>>>(A_log, Ssum, hend);
        scan_part2<64><<<dim3(2048), dim3(256), 0, stream>>>(dtb, xc, xdf, xz, hend, A_log, Dp, Yb);
        g_outproj<<<dim3(16, 8, 4), dim3(512), 0, stream>>>(Yb, owB, Pout);
        red4_ln<<<dim3(T_TOK), dim3(256), 0, stream>>>(Pout, x, ln2g, ln2b, x2, h1);
        g_ffn1<<<dim3(16, 32), dim3(512), 0, stream>>>(h1, fw1B, f1, fb1);
        g_ffn2_4<<<dim3(16, 8, 4), dim3(512), 0, stream>>>(f1, fw2B, Pf);
        red_bias_resid<4><<<dim3(1024), dim3(256), 0, stream>>>(Pf, fb2, x2, out);
    } else {
        bf16* ipB  = (bf16*)(w + (20u << 20));   // pre-conv, xc region free
        bf16* owB  = (bf16*)(w);                 // post-prefix, Ssum dead
        bf16* fw1B = (bf16*)(w + (29u << 20));   // post-scan, dtb dead
        bf16* fw2B = (bf16*)(w + (20u << 20));   // post-outproj, Y dead
        bf16* Pf   = (bf16*)(w + (28u << 20));   // 8MB, KS=2 (xdf/fw1B dead)

        cvtw<<<dim3(2048), dim3(256), 0, stream>>>(in_proj, ipB);
        ln_kernel<<<dim3(T_TOK), dim3(256), 0, stream>>>(x, ln1g, ln1b, h1);
        g_inproj<<<dim3(16, 32), dim3(512), 0, stream>>>(h1, ipB, xz);
        conv_silu<<<dim3(T_TOK * DI / 8 / 256), dim3(256), 0, stream>>>(xz, conv_w, conv_b, xc);
        padw_kernel<<<dim3(128 * 2048 / 256), dim3(256), 0, stream>>>(x_proj, Wpad);
        g_xproj<<<dim3(16, 1, 16), dim3(512), 0, stream>>>(xc, Wpad, Pp);
        reduce16<<<dim3(256), dim3(256), 0, stream>>>(Pp, xdf);
        gemm_dt64<<<dim3(64, 16), dim3(256), 0, stream>>>(xdf, dt_w, dt_b, dtb);
        scan_part1<32><<<dim3(1024), dim3(256), 0, stream>>>(dtb, xc, xdf, A_log, Ssum, hend);
        scan_prefix<32><<<dim3(256), dim3(256), 0, stream>>>(A_log, Ssum, hend);
        cvtw<<<dim3(1024), dim3(256), 0, stream>>>(out_w, owB);
        scan_part2<32><<<dim3(1024), dim3(256), 0, stream>>>(dtb, xc, xdf, xz, hend, A_log, Dp, Yb);
        g_outproj<<<dim3(16, 8, 4), dim3(512), 0, stream>>>(Yb, owB, Pout);
        cvtw<<<dim3(2048), dim3(256), 0, stream>>>(fw1, fw1B);
        red4_ln<<<dim3(T_TOK), dim3(256), 0, stream>>>(Pout, x, ln2g, ln2b, x2, h1);
        g_ffn1<<<dim3(16, 32), dim3(512), 0, stream>>>(h1, fw1B, f1, fb1);
        cvtw<<<dim3(2048), dim3(256), 0, stream>>>(fw2, fw2B);
        g_ffn2_2<<<dim3(16, 8, 2), dim3(512), 0, stream>>>(f1, fw2B, Pf);
        red_bias_resid<2><<<dim3(1024), dim3(256), 0, stream>>>(Pf, fb2, x2, out);
    }
}

// Round 8
// 340.034 us; speedup vs baseline: 1.1093x; 1.0372x over previous
//
#include <hip/hip_runtime.h>
#include <hip/hip_bf16.h>

#define T_TOK 2048   // BATCH*SEQLEN
#define LSEQ  1024
#define DM    1024
#define DI    2048
#define LDW2  72     // LDS row stride for K=64 dt gemm

using bf16 = __hip_bfloat16;
typedef __attribute__((ext_vector_type(8))) short short8;
typedef __attribute__((ext_vector_type(4))) short short4b;
typedef __attribute__((ext_vector_type(4))) float floatx4;

__device__ inline float to_f(float v) { return v; }
__device__ inline float to_f(bf16 v) { return __bfloat162float(v); }
__device__ inline bf16  f2bf(float v) { return __float2bfloat16(v); }
__device__ inline float bf2f(short s) { return __bfloat162float(__builtin_bit_cast(bf16, s)); }

// load 8 contiguous elements as bf16 bit-pattern (converting if fp32 source)
__device__ inline short8 ld8(const bf16* p) { return *(const short8*)p; }
__device__ inline short8 ld8(const float* p) {
    floatx4 f0 = *(const floatx4*)p;
    floatx4 f1 = *(const floatx4*)(p + 4);
    short8 r;
#pragma unroll
    for (int i = 0; i < 4; ++i) {
        r[i]     = __builtin_bit_cast(short, __float2bfloat16(f0[i]));
        r[i + 4] = __builtin_bit_cast(short, __float2bfloat16(f1[i]));
    }
    return r;
}

// async global->LDS, 16B per lane (dest = wave-uniform base + lane*16)
__device__ __forceinline__ void gload16(const void* g, void* l) {
    __builtin_amdgcn_global_load_lds(
        (const __attribute__((address_space(1))) unsigned int*)g,
        (__attribute__((address_space(3))) unsigned int*)l, 16, 0, 0);
}

// Linear [row][64] bf16 tile (128B row = 8x16B slots) with XOR involution
// col ^= (row&7)<<3.  A quarter-wave ds_read_b128 (16 lanes, consecutive
// rows, same col) then spans all 8 slots with exactly 2 lanes each ->
// conflict-free.  Same XOR applied to the GLOBAL source column during
// staging (linear LDS dest, pre-swizzled source — rule 21).
__device__ __forceinline__ int swz64(int row, int col) {
    return row * 64 + (col ^ ((row & 7) << 3));
}

// ---------------------------------------------------------------------------
// GEMM core: C[M,N] = A[M,K] @ W[N,K]^T, both bf16. 128x128 tile, BK=64,
// m97-structure (single LDS buffer, __syncthreads, global_load_lds(16B),
// compiler-scheduled waitcnts). 512 threads = 8 waves (wave tile 64x32,
// acc 4x2). BK=64: 4 gloads/thread in flight per step, HALF the barrier
// crossings of BK=32, 16 MFMAs/wave per step — same traffic, deeper queue.
// LDS 32KB/block (64KB/CU at 2 blocks).
// EPI: 0 bf16 | 2 bf16 softplus(c+bias) | 4 bf16 relu(c+bias)
//      7 fp32 partial @ +bz*zstr | 8 bf16 partial @ +bz*zstr
// ---------------------------------------------------------------------------
template<int EPI, int KS>
__device__ __forceinline__ void gemm_core(
    const bf16* __restrict__ A, int lda,
    const bf16* __restrict__ W, int K,
    float* __restrict__ outF, bf16* __restrict__ outB, int ldc,
    const float* __restrict__ bias, size_t zstr)
{
    __shared__ __align__(16) bf16 sA[128 * 64];
    __shared__ __align__(16) bf16 sW[128 * 64];
    const int tid  = threadIdx.x;              // 0..511
    const int lane = tid & 63, wid = tid >> 6; // 8 waves

    // bijective chunked XCD swizzle (all grids have nwg % 8 == 0)
    const int nwg = gridDim.x * gridDim.y * gridDim.z;
    const int lin = blockIdx.x + gridDim.x * (blockIdx.y + gridDim.y * blockIdx.z);
    const int sid = (lin & 7) * (nwg >> 3) + (lin >> 3);
    const int bx  = sid % gridDim.x;
    const int byz = sid / gridDim.x;
    const int by  = byz % gridDim.y;
    const int bz  = byz / gridDim.y;

    const int m0 = bx * 128, n0 = by * 128;
    const int wm = (wid >> 2) * 64;            // 2 wave-rows
    const int wn = (wid & 3) * 32;             // 4 wave-cols
    const int lr = lane & 15, lh = lane >> 4;

    // staging: 2 issues per matrix; issue i covers rows i*64 + (tid>>3),
    // 8 threads/row, chunk (tid&7)*8 cols, source col pre-swizzled.
    const int r0  = tid >> 3;                  // 0..63
    const int gc0 = ((tid & 7) * 8) ^ ((r0 & 7) << 3);

    const int kBeg = bz * (K / KS);
    const int kEnd = kBeg + K / KS;

    const bf16* Ag0 = A + (size_t)(m0 + r0)      * lda + kBeg + gc0;
    const bf16* Ag1 = A + (size_t)(m0 + r0 + 64) * lda + kBeg + gc0;
    const bf16* Wg0 = W + (size_t)(n0 + r0)      * K   + kBeg + gc0;
    const bf16* Wg1 = W + (size_t)(n0 + r0 + 64) * K   + kBeg + gc0;

    // wave-uniform LDS dests: issue i, wave w -> rows i*64 + w*8 .. +7
    bf16* sA0 = sA + wid * 512;
    bf16* sA1 = sA + 4096 + wid * 512;
    bf16* sW0 = sW + wid * 512;
    bf16* sW1 = sW + 4096 + wid * 512;

    floatx4 acc[4][2];
#pragma unroll
    for (int i = 0; i < 4; ++i)
#pragma unroll
        for (int j = 0; j < 2; ++j) acc[i][j] = (floatx4){0.f, 0.f, 0.f, 0.f};

    for (int k0 = kBeg; k0 < kEnd; k0 += 64) {
        __syncthreads();                 // prev iter's LDS reads complete
        gload16(Ag0, sA0);
        gload16(Ag1, sA1);
        gload16(Wg0, sW0);
        gload16(Wg1, sW1);
        Ag0 += 64; Ag1 += 64; Wg0 += 64; Wg1 += 64;
        __syncthreads();                 // compiler drains vmcnt before barrier

#pragma unroll
        for (int kk = 0; kk < 2; ++kk) {
            short8 af[4], wf[2];
#pragma unroll
            for (int i = 0; i < 4; ++i)
                af[i] = *(const short8*)(sA + swz64(wm + i * 16 + lr, kk * 32 + lh * 8));
#pragma unroll
            for (int j = 0; j < 2; ++j)
                wf[j] = *(const short8*)(sW + swz64(wn + j * 16 + lr, kk * 32 + lh * 8));
#pragma unroll
            for (int i = 0; i < 4; ++i)
#pragma unroll
                for (int j = 0; j < 2; ++j)
                    acc[i][j] = __builtin_amdgcn_mfma_f32_16x16x32_bf16(af[i], wf[j], acc[i][j], 0, 0, 0);
        }
    }

    // epilogue: C/D layout col=lane&15, row=(lane>>4)*4+reg
#pragma unroll
    for (int i = 0; i < 4; ++i) {
#pragma unroll
        for (int j = 0; j < 2; ++j) {
#pragma unroll
            for (int r = 0; r < 4; ++r) {
                int row = m0 + wm + i * 16 + lh * 4 + r;
                int col = n0 + wn + j * 16 + lr;
                size_t off = (size_t)row * ldc + col;
                float c = acc[i][j][r];
                if (EPI == 0) {
                    outB[off] = f2bf(c);
                } else if (EPI == 2) {
                    float v = c + bias[col];
                    outB[off] = f2bf((v > 15.f) ? v : log1pf(__expf(v)));
                } else if (EPI == 4) {
                    float v = c + bias[col];
                    outB[off] = f2bf(v > 0.f ? v : 0.f);
                } else if (EPI == 7) {
                    outF[off + (size_t)bz * zstr] = c;
                } else if (EPI == 8) {
                    outB[off + (size_t)bz * zstr] = f2bf(c);
                }
            }
        }
    }
}

// named wrappers (distinct symbols -> distinct rocprof rows)
__launch_bounds__(512, 4)
__global__ void g_inproj(const bf16* __restrict__ A, const bf16* __restrict__ W,
                         bf16* __restrict__ outB)
{ gemm_core<0, 1>(A, DM, W, DM, nullptr, outB, 4096, nullptr, 0); }

__launch_bounds__(512, 4)
__global__ void g_xproj(const bf16* __restrict__ A, const bf16* __restrict__ W,
                        float* __restrict__ outF)
{ gemm_core<7, 16>(A, DI, W, DI, outF, nullptr, 128, nullptr, (size_t)T_TOK * 128); }

__launch_bounds__(512, 4)
__global__ void g_outproj(const bf16* __restrict__ A, const bf16* __restrict__ W,
                          bf16* __restrict__ outB)
{ gemm_core<8, 4>(A, DI, W, DI, nullptr, outB, DM, nullptr, (size_t)T_TOK * DM); }

__launch_bounds__(512, 4)
__global__ void g_ffn1(const bf16* __restrict__ A, const bf16* __restrict__ W,
                       bf16* __restrict__ outB, const float* __restrict__ bias)
{ gemm_core<4, 1>(A, DM, W, DM, nullptr, outB, 4096, bias, 0); }

__launch_bounds__(512, 4)
__global__ void g_ffn2_4(const bf16* __restrict__ A, const bf16* __restrict__ W,
                         bf16* __restrict__ outB)
{ gemm_core<8, 4>(A, 4096, W, 4096, nullptr, outB, DM, nullptr, (size_t)T_TOK * DM); }

__launch_bounds__(512, 4)
__global__ void g_ffn2_2(const bf16* __restrict__ A, const bf16* __restrict__ W,
                         bf16* __restrict__ outB)
{ gemm_core<8, 2>(A, 4096, W, 4096, nullptr, outB, DM, nullptr, (size_t)T_TOK * DM); }

// fp32 -> bf16 weight conversion (8 elems/thread)
__launch_bounds__(256)
__global__ void cvtw(const float* __restrict__ src, bf16* __restrict__ dst)
{
    size_t i = ((size_t)blockIdx.x * 256 + threadIdx.x) * 8;
    *(short8*)(dst + i) = ld8(src + i);
}

// fused 4-array weight conversion + x_proj pad (roomy mode; one launch)
__launch_bounds__(256)
__global__ void cvtw5(const float* __restrict__ s0, bf16* __restrict__ d0,
                      const float* __restrict__ s1, bf16* __restrict__ d1,
                      const float* __restrict__ s2, bf16* __restrict__ d2,
                      const float* __restrict__ s3, bf16* __restrict__ d3,
                      const float* __restrict__ s4, bf16* __restrict__ d4)
{
    constexpr size_t N0 = (size_t)2 * DI * DM;   // in_proj
    constexpr size_t N1 = (size_t)DM * DI;       // out_w
    constexpr size_t N2 = (size_t)4 * DM * DM;   // fw1
    constexpr size_t N3 = (size_t)DM * 4 * DM;   // fw2
    size_t i = ((size_t)blockIdx.x * 256 + threadIdx.x) * 8;
    if (i < N0) { *(short8*)(d0 + i) = ld8(s0 + i); return; }
    i -= N0;
    if (i < N1) { *(short8*)(d1 + i) = ld8(s1 + i); return; }
    i -= N1;
    if (i < N2) { *(short8*)(d2 + i) = ld8(s2 + i); return; }
    i -= N2;
    if (i < N3) { *(short8*)(d3 + i) = ld8(s3 + i); return; }
    i -= N3;
    // x_proj pad: [96,2048] fp32 -> [128,2048] bf16, zero rows >= 96
    int row = (int)(i >> 11);
    if (row < 96) { *(short8*)(d4 + i) = ld8(s4 + i); }
    else { *(short8*)(d4 + i) = (short8){0,0,0,0,0,0,0,0}; }
}

// ---------------------------------------------------------------------------
// dt GEMM, specialized: dtb = softplus(xdf[:, :64] @ dt_w^T + dt_b)
// M=2048, N=2048, K=64. BM=32, BN=128 -> grid (64,16)=1024 blocks.
// ---------------------------------------------------------------------------
__launch_bounds__(256)
__global__ void gemm_dt64(const float* __restrict__ A,   // xdf [2048,128]
                          const float* __restrict__ W,   // dt_w [2048,64]
                          const float* __restrict__ bias,
                          bf16* __restrict__ outB)       // dtb [2048,2048]
{
    __shared__ __align__(16) bf16 sA[32 * LDW2];
    __shared__ __align__(16) bf16 sW[128 * LDW2];
    const int tid = threadIdx.x;
    const int lane = tid & 63, w = tid >> 6;
    const int m0 = blockIdx.x * 32, n0 = blockIdx.y * 128;

    {   // stage A: 32 rows x 64 cols (1 ld8/thread)
        int ar = tid >> 3, ac = (tid & 7) * 8;
        *(short8*)(sA + ar * LDW2 + ac) = ld8(A + (size_t)(m0 + ar) * 128 + ac);
        // stage W: 128 rows x 64 cols (4 ld8/thread)
        int wr = tid >> 1, wc = (tid & 1) * 32;
        const float* wp = W + (size_t)(n0 + wr) * 64 + wc;
        *(short8*)(sW + wr * LDW2 + wc)      = ld8(wp);
        *(short8*)(sW + wr * LDW2 + wc + 8)  = ld8(wp + 8);
        *(short8*)(sW + wr * LDW2 + wc + 16) = ld8(wp + 16);
        *(short8*)(sW + wr * LDW2 + wc + 24) = ld8(wp + 24);
    }
    __syncthreads();

    const int lr = lane & 15, lh = lane >> 4;
    floatx4 acc[2][2];
#pragma unroll
    for (int i = 0; i < 2; ++i)
#pragma unroll
        for (int j = 0; j < 2; ++j) acc[i][j] = (floatx4){0.f, 0.f, 0.f, 0.f};

#pragma unroll
    for (int kk = 0; kk < 2; ++kk) {
        short8 af[2], wf[2];
#pragma unroll
        for (int i = 0; i < 2; ++i)
            af[i] = *(const short8*)(sA + (i * 16 + lr) * LDW2 + kk * 32 + lh * 8);
#pragma unroll
        for (int j = 0; j < 2; ++j)
            wf[j] = *(const short8*)(sW + (w * 32 + j * 16 + lr) * LDW2 + kk * 32 + lh * 8);
#pragma unroll
        for (int i = 0; i < 2; ++i)
#pragma unroll
            for (int j = 0; j < 2; ++j)
                acc[i][j] = __builtin_amdgcn_mfma_f32_16x16x32_bf16(af[i], wf[j], acc[i][j], 0, 0, 0);
    }

#pragma unroll
    for (int i = 0; i < 2; ++i) {
#pragma unroll
        for (int j = 0; j < 2; ++j) {
#pragma unroll
            for (int r = 0; r < 4; ++r) {
                int row = m0 + i * 16 + lh * 4 + r;
                int col = n0 + w * 32 + j * 16 + lr;
                float v = acc[i][j][r] + bias[col];
                outB[(size_t)row * DI + col] = f2bf((v > 15.f) ? v : log1pf(__expf(v)));
            }
        }
    }
}

// sum 16 split-K fp32 partial slices -> xdf
__launch_bounds__(256)
__global__ void reduce16(const float* __restrict__ P, float* __restrict__ out)
{
    int i = blockIdx.x * 256 + threadIdx.x;            // float4 idx, 65536 total
    const floatx4* P4 = (const floatx4*)P;
    floatx4 s = (floatx4){0.f, 0.f, 0.f, 0.f};
#pragma unroll
    for (int z = 0; z < 16; ++z) s += P4[(size_t)z * 65536 + i];
    ((floatx4*)out)[i] = s;
}

// Fused: x2 = x + sum_{z<4} P[z] ; h1 = LayerNorm(x2; g,b).  Block per token.
__launch_bounds__(256)
__global__ void red4_ln(const bf16* __restrict__ P, const float* __restrict__ x,
                        const float* __restrict__ g, const float* __restrict__ bb,
                        float* __restrict__ x2, bf16* __restrict__ h1)
{
    int t = blockIdx.x, tid = threadIdx.x;
    size_t rowoff = (size_t)t * DM + tid * 4;
    floatx4 xv = *(const floatx4*)(x + rowoff);
    float v[4];
#pragma unroll
    for (int i = 0; i < 4; ++i) v[i] = xv[i];
#pragma unroll
    for (int z = 0; z < 4; ++z) {
        short4b p = *(const short4b*)(P + (size_t)z * T_TOK * DM + rowoff);
#pragma unroll
        for (int i = 0; i < 4; ++i) v[i] += bf2f(p[i]);
    }
    *(floatx4*)(x2 + rowoff) = (floatx4){v[0], v[1], v[2], v[3]};
    float s = v[0] + v[1] + v[2] + v[3];
    float ss = v[0]*v[0] + v[1]*v[1] + v[2]*v[2] + v[3]*v[3];
#pragma unroll
    for (int o = 1; o < 64; o <<= 1) { s += __shfl_xor(s, o); ss += __shfl_xor(ss, o); }
    __shared__ float red[8];
    int lane = tid & 63, wid = tid >> 6;
    if (lane == 0) { red[wid] = s; red[wid + 4] = ss; }
    __syncthreads();
    s  = red[0] + red[1] + red[2] + red[3];
    ss = red[4] + red[5] + red[6] + red[7];
    float mu  = s * (1.f / DM);
    float var = ss * (1.f / DM) - mu * mu;
    float rs  = rsqrtf(var + 1e-5f);
    int c = tid * 4;
    short4b o4;
#pragma unroll
    for (int i = 0; i < 4; ++i)
        o4[i] = __builtin_bit_cast(short, f2bf((v[i] - mu) * rs * g[c + i] + bb[c + i]));
    *(short4b*)(h1 + rowoff) = o4;
}

// out = bias[col] + resid + sum_{z<Z} P[z]
template<int Z>
__launch_bounds__(256)
__global__ void red_bias_resid(const bf16* __restrict__ P, const float* __restrict__ bias,
                               const float* __restrict__ resid, float* __restrict__ out)
{
    size_t base = ((size_t)blockIdx.x * 256 + threadIdx.x) * 8;
    int c = (int)(base & (DM - 1));
    floatx4 b0 = *(const floatx4*)(bias + c);
    floatx4 b1 = *(const floatx4*)(bias + c + 4);
    floatx4 x0 = *(const floatx4*)(resid + base);
    floatx4 x1 = *(const floatx4*)(resid + base + 4);
    float s[8];
#pragma unroll
    for (int j = 0; j < 4; ++j) { s[j] = x0[j] + b0[j]; s[j + 4] = x1[j] + b1[j]; }
#pragma unroll
    for (int z = 0; z < Z; ++z) {
        short8 p = *(const short8*)(P + (size_t)z * T_TOK * DM + base);
#pragma unroll
        for (int j = 0; j < 8; ++j) s[j] += bf2f(p[j]);
    }
    *(floatx4*)(out + base)     = (floatx4){s[0], s[1], s[2], s[3]};
    *(floatx4*)(out + base + 4) = (floatx4){s[4], s[5], s[6], s[7]};
}

// ---------------------------------------------------------------------------
// LayerNorm over 1024 dims (fp32 in/params), one block per token, bf16 out
// ---------------------------------------------------------------------------
__launch_bounds__(256)
__global__ void ln_kernel(const float* __restrict__ x, const float* __restrict__ g,
                          const float* __restrict__ bb, bf16* __restrict__ out)
{
    int t = blockIdx.x, tid = threadIdx.x;
    const float* xr = x + (size_t)t * DM;
    float v[4], s = 0.f, ss = 0.f;
#pragma unroll
    for (int i = 0; i < 4; ++i) {
        v[i] = xr[tid + i * 256];
        s += v[i]; ss += v[i] * v[i];
    }
#pragma unroll
    for (int o = 1; o < 64; o <<= 1) { s += __shfl_xor(s, o); ss += __shfl_xor(ss, o); }
    __shared__ float red[8];
    int lane = tid & 63, wid = tid >> 6;
    if (lane == 0) { red[wid] = s; red[wid + 4] = ss; }
    __syncthreads();
    s  = red[0] + red[1] + red[2] + red[3];
    ss = red[4] + red[5] + red[6] + red[7];
    float mu  = s * (1.f / DM);
    float var = ss * (1.f / DM) - mu * mu;
    float rs  = rsqrtf(var + 1e-5f);
#pragma unroll
    for (int i = 0; i < 4; ++i) {
        int c = tid + i * 256;
        out[(size_t)t * DM + c] = f2bf((v[i] - mu) * rs * g[c] + bb[c]);
    }
}

// ---------------------------------------------------------------------------
// depthwise causal conv (k=4, fp32 weights) + bias + SiLU -> bf16.
// Vectorized: 8 consecutive d per thread (4x short8 loads, 1x short8 store).
// ---------------------------------------------------------------------------
__launch_bounds__(256)
__global__ void conv_silu(const bf16* __restrict__ xz, const float* __restrict__ cw,
                          const float* __restrict__ cb, bf16* __restrict__ xcb)
{
    int idx = (blockIdx.x * 256 + threadIdx.x) * 8;   // T_TOK*DI elems
    int d  = idx & (DI - 1);
    int tk = idx >> 11;
    int t  = tk & (LSEQ - 1);
    const short8 zero = {0, 0, 0, 0, 0, 0, 0, 0};
    short8 x3 = ld8(xz + (size_t)tk * 4096 + d);
    short8 x2 = (t >= 1) ? ld8(xz + (size_t)(tk - 1) * 4096 + d) : zero;
    short8 x1 = (t >= 2) ? ld8(xz + (size_t)(tk - 2) * 4096 + d) : zero;
    short8 x0 = (t >= 3) ? ld8(xz + (size_t)(tk - 3) * 4096 + d) : zero;
    short8 r;
#pragma unroll
    for (int j = 0; j < 8; ++j) {
        floatx4 wv = *(const floatx4*)(cw + (size_t)(d + j) * 4);
        float acc = cb[d + j]
                  + wv[0] * bf2f(x0[j]) + wv[1] * bf2f(x1[j])
                  + wv[2] * bf2f(x2[j]) + wv[3] * bf2f(x3[j]);
        float s = acc / (1.f + __expf(-acc));
        r[j] = __builtin_bit_cast(short, f2bf(s));
    }
    *(short8*)(xcb + idx) = r;
}

// pad x_proj_w fp32 [96,2048] -> bf16 [128,2048] with zero rows (tight mode)
__launch_bounds__(256)
__global__ void padw_kernel(const float* __restrict__ w, bf16* __restrict__ wp)
{
    int idx = blockIdx.x * 256 + threadIdx.x;   // 128*2048
    int row = idx >> 11;
    wp[idx] = (row < 96) ? f2bf(w[idx]) : f2bf(0.f);
}

// ---------------------------------------------------------------------------
// Chunked selective scan, 3 phases, 8 states per thread (2 threads per (b,d)
// chain). Template NCH_: chunk count (roomy=64 for 8 blocks/CU TLP).
// ---------------------------------------------------------------------------
template<int NCH_>
__launch_bounds__(256)
__global__ void scan_part1(const bf16* __restrict__ dt, const bf16* __restrict__ xc,
                           const float* __restrict__ xdbl, const float* __restrict__ A_log,
                           float* __restrict__ Ssum, float* __restrict__ hend)
{
    constexpr int CLEN_ = LSEQ / NCH_;
    constexpr int LOGN  = (NCH_ == 64) ? 6 : 5;
    int G = blockIdx.x * 256 + threadIdx.x;     // 2 * NCH_ * DI * 2
    int half = G & 1;
    int d = (G >> 1) & (DI - 1);
    int c = (G >> 12) & (NCH_ - 1);
    int b = G >> (12 + LOGN);
    int n0 = half * 8;

    floatx4 al0 = *(const floatx4*)(A_log + d * 16 + n0);
    floatx4 al1 = *(const floatx4*)(A_log + d * 16 + n0 + 4);
    float a[8];
#pragma unroll
    for (int j = 0; j < 4; ++j) { a[j] = -__expf(al0[j]); a[j + 4] = -__expf(al1[j]); }

    const bf16*  dt_p = dt   + (size_t)b * LSEQ * DI + d;
    const bf16*  xc_p = xc   + (size_t)b * LSEQ * DI + d;
    const float* xb_p = xdbl + (size_t)b * LSEQ * 128 + 64 + n0;   // B slice

    float h[8];
#pragma unroll
    for (int j = 0; j < 8; ++j) h[j] = 0.f;
    float S = 0.f;

    const int t0 = c * CLEN_;
#pragma unroll 4
    for (int t = t0; t < t0 + CLEN_; ++t) {
        float dtv = to_f(dt_p[(size_t)t * DI]);
        float xv  = to_f(xc_p[(size_t)t * DI]);
        floatx4 B0 = *(const floatx4*)(xb_p + (size_t)t * 128);
        floatx4 B1 = *(const floatx4*)(xb_p + (size_t)t * 128 + 4);
        S += dtv;
        float dx = dtv * xv;
#pragma unroll
        for (int j = 0; j < 4; ++j) {
            h[j]     = fmaf(__expf(dtv * a[j]),     h[j],     dx * B0[j]);
            h[j + 4] = fmaf(__expf(dtv * a[j + 4]), h[j + 4], dx * B1[j]);
        }
    }

    size_t cid = (size_t)(b * NCH_ + c) * DI + d;
    if (half == 0) Ssum[cid] = S;
    float* he = hend + cid * 16 + n0;
    *(floatx4*)he       = (floatx4){h[0], h[1], h[2], h[3]};
    *(floatx4*)(he + 4) = (floatx4){h[4], h[5], h[6], h[7]};
}

template<int NCH_>
__launch_bounds__(256)
__global__ void scan_prefix(const float* __restrict__ A_log, const float* __restrict__ Ssum,
                            float* __restrict__ hend)
{
    int tid = blockIdx.x * 256 + threadIdx.x;   // 2*DI*16 = 65536
    int n = tid & 15;
    int d = (tid >> 4) & (DI - 1);
    int b = tid >> 15;
    float a = -__expf(A_log[d * 16 + n]);

    size_t row = (size_t)b * NCH_ * DI + d;
    float Sc = Ssum[row];
    float E  = hend[row * 16 + n];
    float h = 0.f;
    for (int c = 0; c < NCH_; ++c) {
        size_t nrow = row + DI;
        float Sn = 0.f, En = 0.f;
        if (c + 1 < NCH_) { Sn = Ssum[nrow]; En = hend[nrow * 16 + n]; }
        float P = __expf(a * Sc);
        hend[row * 16 + n] = h;      // becomes hinit for chunk c
        h  = fmaf(P, h, E);
        Sc = Sn; E = En; row = nrow;
    }
}

template<int NCH_>
__launch_bounds__(256)
__global__ void scan_part2(const bf16* __restrict__ dt, const bf16* __restrict__ xc,
                           const float* __restrict__ xdbl, const bf16* __restrict__ xz,
                           const float* __restrict__ hinit, const float* __restrict__ A_log,
                           const float* __restrict__ Dp, bf16* __restrict__ Y)
{
    constexpr int CLEN_ = LSEQ / NCH_;
    constexpr int LOGN  = (NCH_ == 64) ? 6 : 5;
    int G = blockIdx.x * 256 + threadIdx.x;
    int half = G & 1;
    int d = (G >> 1) & (DI - 1);
    int c = (G >> 12) & (NCH_ - 1);
    int b = G >> (12 + LOGN);
    int n0 = half * 8;

    floatx4 al0 = *(const floatx4*)(A_log + d * 16 + n0);
    floatx4 al1 = *(const floatx4*)(A_log + d * 16 + n0 + 4);
    float a[8];
#pragma unroll
    for (int j = 0; j < 4; ++j) { a[j] = -__expf(al0[j]); a[j + 4] = -__expf(al1[j]); }
    float Dd = Dp[d];

    size_t cid = (size_t)(b * NCH_ + c) * DI + d;
    const float* hi = hinit + cid * 16 + n0;
    floatx4 h0 = *(const floatx4*)hi;
    floatx4 h1 = *(const floatx4*)(hi + 4);
    float h[8] = {h0[0], h0[1], h0[2], h0[3], h1[0], h1[1], h1[2], h1[3]};

    const bf16*  dt_p = dt   + (size_t)b * LSEQ * DI + d;
    const bf16*  xc_p = xc   + (size_t)b * LSEQ * DI + d;
    const float* xb_p = xdbl + (size_t)b * LSEQ * 128 + 64 + n0;   // B slice
    const float* xcc_p= xdbl + (size_t)b * LSEQ * 128 + 80 + n0;   // C slice
    const bf16*  z_p  = xz   + (size_t)b * LSEQ * 4096 + DI + d;
    bf16* y_p = Y + (size_t)b * LSEQ * DI + d;

    const int t0 = c * CLEN_;
#pragma unroll 4
    for (int t = t0; t < t0 + CLEN_; ++t) {
        float dtv = to_f(dt_p[(size_t)t * DI]);
        float xv  = to_f(xc_p[(size_t)t * DI]);
        float zv  = to_f(z_p[(size_t)t * 4096]);
        floatx4 B0 = *(const floatx4*)(xb_p  + (size_t)t * 128);
        floatx4 B1 = *(const floatx4*)(xb_p  + (size_t)t * 128 + 4);
        floatx4 C0 = *(const floatx4*)(xcc_p + (size_t)t * 128);
        floatx4 C1 = *(const floatx4*)(xcc_p + (size_t)t * 128 + 4);
        float dx = dtv * xv;
        float p = 0.f;
#pragma unroll
        for (int j = 0; j < 4; ++j) {
            h[j]     = fmaf(__expf(dtv * a[j]),     h[j],     dx * B0[j]);
            p = fmaf(h[j], C0[j], p);
            h[j + 4] = fmaf(__expf(dtv * a[j + 4]), h[j + 4], dx * B1[j]);
            p = fmaf(h[j + 4], C1[j], p);
        }
        p += __shfl_xor(p, 1);      // combine the two 8-state halves
        if (half == 0) {
            float pp = p + Dd * xv;
            float sz = zv / (1.f + __expf(-zv));
            y_p[(size_t)t * DI] = f2bf(pp * sz);
        }
    }
}

// ---------------------------------------------------------------------------
extern "C" void kernel_launch(void* const* d_in, const int* in_sizes, int n_in,
                              void* d_out, int out_size, void* d_ws, size_t ws_size,
                              hipStream_t stream)
{
    const float* x       = (const float*)d_in[0];
    const float* in_proj = (const float*)d_in[1];
    const float* conv_w  = (const float*)d_in[2];
    const float* conv_b  = (const float*)d_in[3];
    const float* x_proj  = (const float*)d_in[4];
    const float* dt_w    = (const float*)d_in[5];
    const float* dt_b    = (const float*)d_in[6];
    const float* A_log   = (const float*)d_in[7];
    const float* Dp      = (const float*)d_in[8];
    const float* out_w   = (const float*)d_in[9];
    const float* ln1g    = (const float*)d_in[10];
    const float* ln1b    = (const float*)d_in[11];
    const float* ln2g    = (const float*)d_in[12];
    const float* ln2b    = (const float*)d_in[13];
    const float* fw1     = (const float*)d_in[14];
    const float* fb1     = (const float*)d_in[15];
    const float* fw2     = (const float*)d_in[16];
    const float* fb2     = (const float*)d_in[17];
    float* out = (float*)d_out;

    // Base workspace layout (lifetime-aliased):
    //  @0    4MB   h1 / Ssum (<=1MB)
    //  @4    16MB  xz -> Pout -> f1
    //  @20   8MB   xc (-> Y in-place)   | at ffn2: Pf @20..36
    //  @28   1MB   xdf
    //  @29   8MB   dtb                  | step5: Pp fp32 partials @29..45
    //  @37   hend (roomy NCH=64: 16MB @37..53, ipB dead by then) -> x2 @37..45
    //  @45   0.5MB Wpad
    // Roomy (ws >= 74MB): bf16 weights ipB@46 owB@54 fw1B@58 fw2B@66.
    char* w = (char*)d_ws;
    bf16*  h1   = (bf16*)(w);
    bf16*  xz   = (bf16*)(w + (4u  << 20));
    bf16*  xc   = (bf16*)(w + (20u << 20));
    float* xdf  = (float*)(w + (28u << 20));
    bf16*  dtb  = (bf16*)(w + (29u << 20));
    float* Pp   = (float*)(w + (29u << 20));   // 16MB fp32 partials (xproj)
    float* hend = (float*)(w + (37u << 20));
    float* x2   = (float*)(w + (37u << 20));
    bf16*  Wpad = (bf16*)(w + (45u << 20));
    float* Ssum = (float*)(w);
    bf16*  Pout = (bf16*)(w + (4u  << 20));    // 16MB bf16 partials (outproj)
    bf16*  Yb = xc;
    bf16*  f1 = xz;

    const bool roomy = ws_size >= ((size_t)74 << 20);

    if (roomy) {
        bf16* ipB  = (bf16*)(w + (46u << 20));   // 8MB
        bf16* owB  = (bf16*)(w + (54u << 20));   // 4MB
        bf16* fw1B = (bf16*)(w + (58u << 20));   // 8MB
        bf16* fw2B = (bf16*)(w + (66u << 20));   // 8MB
        bf16* Pf   = (bf16*)(w + (20u << 20));   // 16MB (xc/xdf/dtb dead at ffn2)

        cvtw5<<<dim3(7296), dim3(256), 0, stream>>>(in_proj, ipB, out_w, owB,
                                                    fw1, fw1B, fw2, fw2B, x_proj, Wpad);
        ln_kernel<<<dim3(T_TOK), dim3(256), 0, stream>>>(x, ln1g, ln1b, h1);
        g_inproj<<<dim3(16, 32), dim3(512), 0, stream>>>(h1, ipB, xz);
        conv_silu<<<dim3(T_TOK * DI / 8 / 256), dim3(256), 0, stream>>>(xz, conv_w, conv_b, xc);
        g_xproj<<<dim3(16, 1, 16), dim3(512), 0, stream>>>(xc, Wpad, Pp);
        reduce16<<<dim3(256), dim3(256), 0, stream>>>(Pp, xdf);
        gemm_dt64<<<dim3(64, 16), dim3(256), 0, stream>>>(xdf, dt_w, dt_b, dtb);
        scan_part1<64><<<dim3(2048), dim3(256), 0, stream>>>(dtb, xc, xdf, A_log, Ssum, hend);
        scan_prefix<64><<<dim3(256), dim3(256), 0, stream>>>(A_log, Ssum, hend);
        scan_part2<64><<<dim3(2048), dim3(256), 0, stream>>>(dtb, xc, xdf, xz, hend, A_log, Dp, Yb);
        g_outproj<<<dim3(16, 8, 4), dim3(512), 0, stream>>>(Yb, owB, Pout);
        red4_ln<<<dim3(T_TOK), dim3(256), 0, stream>>>(Pout, x, ln2g, ln2b, x2, h1);
        g_ffn1<<<dim3(16, 32), dim3(512), 0, stream>>>(h1, fw1B, f1, fb1);
        g_ffn2_4<<<dim3(16, 8, 4), dim3(512), 0, stream>>>(f1, fw2B, Pf);
        red_bias_resid<4><<<dim3(1024), dim3(256), 0, stream>>>(Pf, fb2, x2, out);
    } else {
        bf16* ipB  = (bf16*)(w + (20u << 20));   // pre-conv, xc region free
        bf16* owB  = (bf16*)(w);                 // post-prefix, Ssum dead
        bf16* fw1B = (bf16*)(w + (29u << 20));   // post-scan, dtb dead
        bf16* fw2B = (bf16*)(w + (20u << 20));   // post-outproj, Y dead
        bf16* Pf   = (bf16*)(w + (28u << 20));   // 8MB, KS=2 (xdf/fw1B dead)

        cvtw<<<dim3(2048), dim3(256), 0, stream>>>(in_proj, ipB);
        ln_kernel<<<dim3(T_TOK), dim3(256), 0, stream>>>(x, ln1g, ln1b, h1);
        g_inproj<<<dim3(16, 32), dim3(512), 0, stream>>>(h1, ipB, xz);
        conv_silu<<<dim3(T_TOK * DI / 8 / 256), dim3(256), 0, stream>>>(xz, conv_w, conv_b, xc);
        padw_kernel<<<dim3(128 * 2048 / 256), dim3(256), 0, stream>>>(x_proj, Wpad);
        g_xproj<<<dim3(16, 1, 16), dim3(512), 0, stream>>>(xc, Wpad, Pp);
        reduce16<<<dim3(256), dim3(256), 0, stream>>>(Pp, xdf);
        gemm_dt64<<<dim3(64, 16), dim3(256), 0, stream>>>(xdf, dt_w, dt_b, dtb);
        scan_part1<32><<<dim3(1024), dim3(256), 0, stream>>>(dtb, xc, xdf, A_log, Ssum, hend);
        scan_prefix<32><<<dim3(256), dim3(256), 0, stream>>>(A_log, Ssum, hend);
        cvtw<<<dim3(1024), dim3(256), 0, stream>>>(out_w, owB);
        scan_part2<32><<<dim3(1024), dim3(256), 0, stream>>>(dtb, xc, xdf, xz, hend, A_log, Dp, Yb);
        g_outproj<<<dim3(16, 8, 4), dim3(512), 0, stream>>>(Yb, owB, Pout);
        cvtw<<<dim3(2048), dim3(256), 0, stream>>>(fw1, fw1B);
        red4_ln<<<dim3(T_TOK), dim3(256), 0, stream>>>(Pout, x, ln2g, ln2b, x2, h1);
        g_ffn1<<<dim3(16, 32), dim3(512), 0, stream>>>(h1, fw1B, f1, fb1);
        cvtw<<<dim3(2048), dim3(256), 0, stream>>>(fw2, fw2B);
        g_ffn2_2<<<dim3(16, 8, 2), dim3(512), 0, stream>>>(f1, fw2B, Pf);
        red_bias_resid<2><<<dim3(1024), dim3(256), 0, stream>>>(Pf, fb2, x2, out);
    }
}

// Round 9
// 333.976 us; speedup vs baseline: 1.1295x; 1.0181x over previous
//
#include <hip/hip_runtime.h>
#include <hip/hip_bf16.h>

#define T_TOK 2048   // BATCH*SEQLEN
#define LSEQ  1024
#define DM    1024
#define DI    2048
#define LDW2  72     // LDS row stride for K=64 dt gemm

using bf16 = __hip_bfloat16;
typedef __attribute__((ext_vector_type(8))) short short8;
typedef __attribute__((ext_vector_type(4))) short short4b;
typedef __attribute__((ext_vector_type(4))) float floatx4;

__device__ inline float to_f(float v) { return v; }
__device__ inline float to_f(bf16 v) { return __bfloat162float(v); }
__device__ inline bf16  f2bf(float v) { return __float2bfloat16(v); }
__device__ inline float bf2f(short s) { return __bfloat162float(__builtin_bit_cast(bf16, s)); }

// load 8 contiguous elements as bf16 bit-pattern (converting if fp32 source)
__device__ inline short8 ld8(const bf16* p) { return *(const short8*)p; }
__device__ inline short8 ld8(const float* p) {
    floatx4 f0 = *(const floatx4*)p;
    floatx4 f1 = *(const floatx4*)(p + 4);
    short8 r;
#pragma unroll
    for (int i = 0; i < 4; ++i) {
        r[i]     = __builtin_bit_cast(short, __float2bfloat16(f0[i]));
        r[i + 4] = __builtin_bit_cast(short, __float2bfloat16(f1[i]));
    }
    return r;
}

// async global->LDS, 16B per lane (dest = wave-uniform base + lane*16)
__device__ __forceinline__ void gload16(const void* g, void* l) {
    __builtin_amdgcn_global_load_lds(
        (const __attribute__((address_space(1))) unsigned int*)g,
        (__attribute__((address_space(3))) unsigned int*)l, 16, 0, 0);
}

// Linear [row][64] bf16 tile (128B row = 8x16B slots) with XOR involution
// col ^= (row&7)<<3.  A quarter-wave ds_read_b128 (16 lanes, consecutive
// rows, same col) then spans all 8 slots with exactly 2 lanes each ->
// conflict-free.  Same XOR applied to the GLOBAL source column during
// staging (linear LDS dest, pre-swizzled source — rule 21).
__device__ __forceinline__ int swz64(int row, int col) {
    return row * 64 + (col ^ ((row & 7) << 3));
}

// ---------------------------------------------------------------------------
// GEMM core: C[M,N] = A[M,K] @ W[N,K]^T, both bf16. 128x128 tile, BK=64,
// 512 threads = 8 waves (wave tile 64x32, acc 4x2), global_load_lds(16B).
// T3 minimum-2-phase pipeline in PURE HIP (no sched_barrier — that was R5's
// m141-style regression):
//   prologue: STAGE(buf0); __syncthreads();
//   loop:     STAGE(buf^1, k+64); COMPUTE(buf); __syncthreads(); swap
// __syncthreads() IS "vmcnt(0)+barrier", so the prefetch issued BEFORE the
// compute overlaps its HBM latency with 16 MFMAs + ds_reads, and there is
// ONE barrier per K-step (was 2). Double-buffer LDS = 64KB/block is free:
// grids cap us at 2 blocks/CU anyway (128KB/CU < 160).
// All K-step counts are even (2/8/16) -> compile-time buffer parity.
// EPI: 0 bf16 | 2 bf16 softplus(c+bias) | 4 bf16 relu(c+bias)
//      7 fp32 partial @ +bz*zstr | 8 bf16 partial @ +bz*zstr
// ---------------------------------------------------------------------------
template<int EPI, int KS>
__device__ __forceinline__ void gemm_core(
    const bf16* __restrict__ A, int lda,
    const bf16* __restrict__ W, int K,
    float* __restrict__ outF, bf16* __restrict__ outB, int ldc,
    const float* __restrict__ bias, size_t zstr)
{
    __shared__ __align__(16) bf16 sA[2 * 128 * 64];
    __shared__ __align__(16) bf16 sW[2 * 128 * 64];
    const int tid  = threadIdx.x;              // 0..511
    const int lane = tid & 63, wid = tid >> 6; // 8 waves

    // bijective chunked XCD swizzle (all grids have nwg % 8 == 0)
    const int nwg = gridDim.x * gridDim.y * gridDim.z;
    const int lin = blockIdx.x + gridDim.x * (blockIdx.y + gridDim.y * blockIdx.z);
    const int sid = (lin & 7) * (nwg >> 3) + (lin >> 3);
    const int bx  = sid % gridDim.x;
    const int byz = sid / gridDim.x;
    const int by  = byz % gridDim.y;
    const int bz  = byz / gridDim.y;

    const int m0 = bx * 128, n0 = by * 128;
    const int wm = (wid >> 2) * 64;            // 2 wave-rows
    const int wn = (wid & 3) * 32;             // 4 wave-cols
    const int lr = lane & 15, lh = lane >> 4;

    // staging: issue i covers rows i*64 + (tid>>3), 8 threads/row,
    // chunk (tid&7)*8 cols, source col pre-swizzled.
    const int r0  = tid >> 3;                  // 0..63
    const int gc0 = ((tid & 7) * 8) ^ ((r0 & 7) << 3);

    const int kBeg = bz * (K / KS);
    const int kEnd = kBeg + K / KS;

    const bf16* Ag0 = A + (size_t)(m0 + r0)      * lda + kBeg + gc0;
    const bf16* Ag1 = A + (size_t)(m0 + r0 + 64) * lda + kBeg + gc0;
    const bf16* Wg0 = W + (size_t)(n0 + r0)      * K   + kBeg + gc0;
    const bf16* Wg1 = W + (size_t)(n0 + r0 + 64) * K   + kBeg + gc0;

    floatx4 acc[4][2];
#pragma unroll
    for (int i = 0; i < 4; ++i)
#pragma unroll
        for (int j = 0; j < 2; ++j) acc[i][j] = (floatx4){0.f, 0.f, 0.f, 0.f};

    // B = buffer (0/1), KOFF = k offset relative to kBeg
#define STAGE(B, KOFF) do {                                           \
        gload16(Ag0 + (KOFF), sA + (B) * 8192 + wid * 512);           \
        gload16(Ag1 + (KOFF), sA + (B) * 8192 + 4096 + wid * 512);    \
        gload16(Wg0 + (KOFF), sW + (B) * 8192 + wid * 512);           \
        gload16(Wg1 + (KOFF), sW + (B) * 8192 + 4096 + wid * 512);    \
    } while (0)

#define COMPUTE(B) do {                                                        \
        const bf16* bA = sA + (B) * 8192;                                      \
        const bf16* bW = sW + (B) * 8192;                                      \
        _Pragma("unroll")                                                      \
        for (int kk = 0; kk < 2; ++kk) {                                       \
            short8 af[4], wf[2];                                               \
            _Pragma("unroll")                                                  \
            for (int i = 0; i < 4; ++i)                                        \
                af[i] = *(const short8*)(bA + swz64(wm + i * 16 + lr,          \
                                                    kk * 32 + lh * 8));        \
            _Pragma("unroll")                                                  \
            for (int j = 0; j < 2; ++j)                                        \
                wf[j] = *(const short8*)(bW + swz64(wn + j * 16 + lr,          \
                                                    kk * 32 + lh * 8));        \
            _Pragma("unroll")                                                  \
            for (int i = 0; i < 4; ++i)                                        \
                _Pragma("unroll")                                              \
                for (int j = 0; j < 2; ++j)                                    \
                    acc[i][j] = __builtin_amdgcn_mfma_f32_16x16x32_bf16(       \
                        af[i], wf[j], acc[i][j], 0, 0, 0);                     \
        }                                                                      \
    } while (0)

    // prologue
    STAGE(0, 0);
    __syncthreads();
    // main loop, unrolled x2 for compile-time buffer parity (steps even)
    for (int k0 = kBeg; k0 < kEnd; k0 += 128) {
        int koff = k0 - kBeg;
        if (k0 + 64 < kEnd) STAGE(1, koff + 64);
        COMPUTE(0);
        __syncthreads();
        if (k0 + 128 < kEnd) STAGE(0, koff + 128);
        COMPUTE(1);
        __syncthreads();
    }
#undef STAGE
#undef COMPUTE

    // epilogue: C/D layout col=lane&15, row=(lane>>4)*4+reg
#pragma unroll
    for (int i = 0; i < 4; ++i) {
#pragma unroll
        for (int j = 0; j < 2; ++j) {
#pragma unroll
            for (int r = 0; r < 4; ++r) {
                int row = m0 + wm + i * 16 + lh * 4 + r;
                int col = n0 + wn + j * 16 + lr;
                size_t off = (size_t)row * ldc + col;
                float c = acc[i][j][r];
                if (EPI == 0) {
                    outB[off] = f2bf(c);
                } else if (EPI == 2) {
                    float v = c + bias[col];
                    outB[off] = f2bf((v > 15.f) ? v : log1pf(__expf(v)));
                } else if (EPI == 4) {
                    float v = c + bias[col];
                    outB[off] = f2bf(v > 0.f ? v : 0.f);
                } else if (EPI == 7) {
                    outF[off + (size_t)bz * zstr] = c;
                } else if (EPI == 8) {
                    outB[off + (size_t)bz * zstr] = f2bf(c);
                }
            }
        }
    }
}

// named wrappers (distinct symbols -> distinct rocprof rows)
__launch_bounds__(512, 4)
__global__ void g_inproj(const bf16* __restrict__ A, const bf16* __restrict__ W,
                         bf16* __restrict__ outB)
{ gemm_core<0, 1>(A, DM, W, DM, nullptr, outB, 4096, nullptr, 0); }

__launch_bounds__(512, 4)
__global__ void g_xproj(const bf16* __restrict__ A, const bf16* __restrict__ W,
                        float* __restrict__ outF)
{ gemm_core<7, 16>(A, DI, W, DI, outF, nullptr, 128, nullptr, (size_t)T_TOK * 128); }

__launch_bounds__(512, 4)
__global__ void g_outproj(const bf16* __restrict__ A, const bf16* __restrict__ W,
                          bf16* __restrict__ outB)
{ gemm_core<8, 4>(A, DI, W, DI, nullptr, outB, DM, nullptr, (size_t)T_TOK * DM); }

__launch_bounds__(512, 4)
__global__ void g_ffn1(const bf16* __restrict__ A, const bf16* __restrict__ W,
                       bf16* __restrict__ outB, const float* __restrict__ bias)
{ gemm_core<4, 1>(A, DM, W, DM, nullptr, outB, 4096, bias, 0); }

__launch_bounds__(512, 4)
__global__ void g_ffn2_4(const bf16* __restrict__ A, const bf16* __restrict__ W,
                         bf16* __restrict__ outB)
{ gemm_core<8, 4>(A, 4096, W, 4096, nullptr, outB, DM, nullptr, (size_t)T_TOK * DM); }

__launch_bounds__(512, 4)
__global__ void g_ffn2_2(const bf16* __restrict__ A, const bf16* __restrict__ W,
                         bf16* __restrict__ outB)
{ gemm_core<8, 2>(A, 4096, W, 4096, nullptr, outB, DM, nullptr, (size_t)T_TOK * DM); }

// fp32 -> bf16 weight conversion (8 elems/thread)
__launch_bounds__(256)
__global__ void cvtw(const float* __restrict__ src, bf16* __restrict__ dst)
{
    size_t i = ((size_t)blockIdx.x * 256 + threadIdx.x) * 8;
    *(short8*)(dst + i) = ld8(src + i);
}

// ---------------------------------------------------------------------------
// Fused LN1 + 4-weight conversion + x_proj pad (roomy mode; ONE launch).
// Blocks [0, T_TOK): LayerNorm of token t.  Blocks [T_TOK, T_TOK+7296): cvt.
// ---------------------------------------------------------------------------
__launch_bounds__(256)
__global__ void pre_ln_cvt(const float* __restrict__ x, const float* __restrict__ g,
                           const float* __restrict__ bb, bf16* __restrict__ h1,
                           const float* __restrict__ s0, bf16* __restrict__ d0,
                           const float* __restrict__ s1, bf16* __restrict__ d1,
                           const float* __restrict__ s2, bf16* __restrict__ d2,
                           const float* __restrict__ s3, bf16* __restrict__ d3,
                           const float* __restrict__ s4, bf16* __restrict__ d4)
{
    int blk = blockIdx.x, tid = threadIdx.x;
    if (blk < T_TOK) {
        // LayerNorm
        const float* xr = x + (size_t)blk * DM;
        float v[4], s = 0.f, ss = 0.f;
#pragma unroll
        for (int i = 0; i < 4; ++i) {
            v[i] = xr[tid + i * 256];
            s += v[i]; ss += v[i] * v[i];
        }
#pragma unroll
        for (int o = 1; o < 64; o <<= 1) { s += __shfl_xor(s, o); ss += __shfl_xor(ss, o); }
        __shared__ float red[8];
        int lane = tid & 63, wid = tid >> 6;
        if (lane == 0) { red[wid] = s; red[wid + 4] = ss; }
        __syncthreads();
        s  = red[0] + red[1] + red[2] + red[3];
        ss = red[4] + red[5] + red[6] + red[7];
        float mu  = s * (1.f / DM);
        float var = ss * (1.f / DM) - mu * mu;
        float rs  = rsqrtf(var + 1e-5f);
#pragma unroll
        for (int i = 0; i < 4; ++i) {
            int c = tid + i * 256;
            h1[(size_t)blk * DM + c] = f2bf((v[i] - mu) * rs * g[c] + bb[c]);
        }
        return;
    }
    constexpr size_t N0 = (size_t)2 * DI * DM;   // in_proj
    constexpr size_t N1 = (size_t)DM * DI;       // out_w
    constexpr size_t N2 = (size_t)4 * DM * DM;   // fw1
    constexpr size_t N3 = (size_t)DM * 4 * DM;   // fw2
    size_t i = ((size_t)(blk - T_TOK) * 256 + tid) * 8;
    if (i < N0) { *(short8*)(d0 + i) = ld8(s0 + i); return; }
    i -= N0;
    if (i < N1) { *(short8*)(d1 + i) = ld8(s1 + i); return; }
    i -= N1;
    if (i < N2) { *(short8*)(d2 + i) = ld8(s2 + i); return; }
    i -= N2;
    if (i < N3) { *(short8*)(d3 + i) = ld8(s3 + i); return; }
    i -= N3;
    // x_proj pad: [96,2048] fp32 -> [128,2048] bf16, zero rows >= 96
    int row = (int)(i >> 11);
    if (row < 96) { *(short8*)(d4 + i) = ld8(s4 + i); }
    else { *(short8*)(d4 + i) = (short8){0,0,0,0,0,0,0,0}; }
}

// ---------------------------------------------------------------------------
// dt GEMM, specialized: dtb = softplus(xdf[:, :64] @ dt_w^T + dt_b)
// M=2048, N=2048, K=64. BM=32, BN=128 -> grid (64,16)=1024 blocks.
// ---------------------------------------------------------------------------
__launch_bounds__(256)
__global__ void gemm_dt64(const float* __restrict__ A,   // xdf [2048,128]
                          const float* __restrict__ W,   // dt_w [2048,64]
                          const float* __restrict__ bias,
                          bf16* __restrict__ outB)       // dtb [2048,2048]
{
    __shared__ __align__(16) bf16 sA[32 * LDW2];
    __shared__ __align__(16) bf16 sW[128 * LDW2];
    const int tid = threadIdx.x;
    const int lane = tid & 63, w = tid >> 6;
    const int m0 = blockIdx.x * 32, n0 = blockIdx.y * 128;

    {   // stage A: 32 rows x 64 cols (1 ld8/thread)
        int ar = tid >> 3, ac = (tid & 7) * 8;
        *(short8*)(sA + ar * LDW2 + ac) = ld8(A + (size_t)(m0 + ar) * 128 + ac);
        // stage W: 128 rows x 64 cols (4 ld8/thread)
        int wr = tid >> 1, wc = (tid & 1) * 32;
        const float* wp = W + (size_t)(n0 + wr) * 64 + wc;
        *(short8*)(sW + wr * LDW2 + wc)      = ld8(wp);
        *(short8*)(sW + wr * LDW2 + wc + 8)  = ld8(wp + 8);
        *(short8*)(sW + wr * LDW2 + wc + 16) = ld8(wp + 16);
        *(short8*)(sW + wr * LDW2 + wc + 24) = ld8(wp + 24);
    }
    __syncthreads();

    const int lr = lane & 15, lh = lane >> 4;
    floatx4 acc[2][2];
#pragma unroll
    for (int i = 0; i < 2; ++i)
#pragma unroll
        for (int j = 0; j < 2; ++j) acc[i][j] = (floatx4){0.f, 0.f, 0.f, 0.f};

#pragma unroll
    for (int kk = 0; kk < 2; ++kk) {
        short8 af[2], wf[2];
#pragma unroll
        for (int i = 0; i < 2; ++i)
            af[i] = *(const short8*)(sA + (i * 16 + lr) * LDW2 + kk * 32 + lh * 8);
#pragma unroll
        for (int j = 0; j < 2; ++j)
            wf[j] = *(const short8*)(sW + (w * 32 + j * 16 + lr) * LDW2 + kk * 32 + lh * 8);
#pragma unroll
        for (int i = 0; i < 2; ++i)
#pragma unroll
            for (int j = 0; j < 2; ++j)
                acc[i][j] = __builtin_amdgcn_mfma_f32_16x16x32_bf16(af[i], wf[j], acc[i][j], 0, 0, 0);
    }

#pragma unroll
    for (int i = 0; i < 2; ++i) {
#pragma unroll
        for (int j = 0; j < 2; ++j) {
#pragma unroll
            for (int r = 0; r < 4; ++r) {
                int row = m0 + i * 16 + lh * 4 + r;
                int col = n0 + w * 32 + j * 16 + lr;
                float v = acc[i][j][r] + bias[col];
                outB[(size_t)row * DI + col] = f2bf((v > 15.f) ? v : log1pf(__expf(v)));
            }
        }
    }
}

// sum 16 split-K fp32 partial slices -> xdf
__launch_bounds__(256)
__global__ void reduce16(const float* __restrict__ P, float* __restrict__ out)
{
    int i = blockIdx.x * 256 + threadIdx.x;            // float4 idx, 65536 total
    const floatx4* P4 = (const floatx4*)P;
    floatx4 s = (floatx4){0.f, 0.f, 0.f, 0.f};
#pragma unroll
    for (int z = 0; z < 16; ++z) s += P4[(size_t)z * 65536 + i];
    ((floatx4*)out)[i] = s;
}

// Fused: x2 = x + sum_{z<4} P[z] ; h1 = LayerNorm(x2; g,b).  Block per token.
__launch_bounds__(256)
__global__ void red4_ln(const bf16* __restrict__ P, const float* __restrict__ x,
                        const float* __restrict__ g, const float* __restrict__ bb,
                        float* __restrict__ x2, bf16* __restrict__ h1)
{
    int t = blockIdx.x, tid = threadIdx.x;
    size_t rowoff = (size_t)t * DM + tid * 4;
    floatx4 xv = *(const floatx4*)(x + rowoff);
    float v[4];
#pragma unroll
    for (int i = 0; i < 4; ++i) v[i] = xv[i];
#pragma unroll
    for (int z = 0; z < 4; ++z) {
        short4b p = *(const short4b*)(P + (size_t)z * T_TOK * DM + rowoff);
#pragma unroll
        for (int i = 0; i < 4; ++i) v[i] += bf2f(p[i]);
    }
    *(floatx4*)(x2 + rowoff) = (floatx4){v[0], v[1], v[2], v[3]};
    float s = v[0] + v[1] + v[2] + v[3];
    float ss = v[0]*v[0] + v[1]*v[1] + v[2]*v[2] + v[3]*v[3];
#pragma unroll
    for (int o = 1; o < 64; o <<= 1) { s += __shfl_xor(s, o); ss += __shfl_xor(ss, o); }
    __shared__ float red[8];
    int lane = tid & 63, wid = tid >> 6;
    if (lane == 0) { red[wid] = s; red[wid + 4] = ss; }
    __syncthreads();
    s  = red[0] + red[1] + red[2] + red[3];
    ss = red[4] + red[5] + red[6] + red[7];
    float mu  = s * (1.f / DM);
    float var = ss * (1.f / DM) - mu * mu;
    float rs  = rsqrtf(var + 1e-5f);
    int c = tid * 4;
    short4b o4;
#pragma unroll
    for (int i = 0; i < 4; ++i)
        o4[i] = __builtin_bit_cast(short, f2bf((v[i] - mu) * rs * g[c + i] + bb[c + i]));
    *(short4b*)(h1 + rowoff) = o4;
}

// out = bias[col] + resid + sum_{z<Z} P[z]
template<int Z>
__launch_bounds__(256)
__global__ void red_bias_resid(const bf16* __restrict__ P, const float* __restrict__ bias,
                               const float* __restrict__ resid, float* __restrict__ out)
{
    size_t base = ((size_t)blockIdx.x * 256 + threadIdx.x) * 8;
    int c = (int)(base & (DM - 1));
    floatx4 b0 = *(const floatx4*)(bias + c);
    floatx4 b1 = *(const floatx4*)(bias + c + 4);
    floatx4 x0 = *(const floatx4*)(resid + base);
    floatx4 x1 = *(const floatx4*)(resid + base + 4);
    float s[8];
#pragma unroll
    for (int j = 0; j < 4; ++j) { s[j] = x0[j] + b0[j]; s[j + 4] = x1[j] + b1[j]; }
#pragma unroll
    for (int z = 0; z < Z; ++z) {
        short8 p = *(const short8*)(P + (size_t)z * T_TOK * DM + base);
#pragma unroll
        for (int j = 0; j < 8; ++j) s[j] += bf2f(p[j]);
    }
    *(floatx4*)(out + base)     = (floatx4){s[0], s[1], s[2], s[3]};
    *(floatx4*)(out + base + 4) = (floatx4){s[4], s[5], s[6], s[7]};
}

// ---------------------------------------------------------------------------
// LayerNorm over 1024 dims (fp32 in/params), one block per token, bf16 out
// (tight mode only; roomy uses pre_ln_cvt)
// ---------------------------------------------------------------------------
__launch_bounds__(256)
__global__ void ln_kernel(const float* __restrict__ x, const float* __restrict__ g,
                          const float* __restrict__ bb, bf16* __restrict__ out)
{
    int t = blockIdx.x, tid = threadIdx.x;
    const float* xr = x + (size_t)t * DM;
    float v[4], s = 0.f, ss = 0.f;
#pragma unroll
    for (int i = 0; i < 4; ++i) {
        v[i] = xr[tid + i * 256];
        s += v[i]; ss += v[i] * v[i];
    }
#pragma unroll
    for (int o = 1; o < 64; o <<= 1) { s += __shfl_xor(s, o); ss += __shfl_xor(ss, o); }
    __shared__ float red[8];
    int lane = tid & 63, wid = tid >> 6;
    if (lane == 0) { red[wid] = s; red[wid + 4] = ss; }
    __syncthreads();
    s  = red[0] + red[1] + red[2] + red[3];
    ss = red[4] + red[5] + red[6] + red[7];
    float mu  = s * (1.f / DM);
    float var = ss * (1.f / DM) - mu * mu;
    float rs  = rsqrtf(var + 1e-5f);
#pragma unroll
    for (int i = 0; i < 4; ++i) {
        int c = tid + i * 256;
        out[(size_t)t * DM + c] = f2bf((v[i] - mu) * rs * g[c] + bb[c]);
    }
}

// ---------------------------------------------------------------------------
// depthwise causal conv (k=4, fp32 weights) + bias + SiLU -> bf16.
// Vectorized: 8 consecutive d per thread (4x short8 loads, 1x short8 store).
// ---------------------------------------------------------------------------
__launch_bounds__(256)
__global__ void conv_silu(const bf16* __restrict__ xz, const float* __restrict__ cw,
                          const float* __restrict__ cb, bf16* __restrict__ xcb)
{
    int idx = (blockIdx.x * 256 + threadIdx.x) * 8;   // T_TOK*DI elems
    int d  = idx & (DI - 1);
    int tk = idx >> 11;
    int t  = tk & (LSEQ - 1);
    const short8 zero = {0, 0, 0, 0, 0, 0, 0, 0};
    short8 x3 = ld8(xz + (size_t)tk * 4096 + d);
    short8 x2 = (t >= 1) ? ld8(xz + (size_t)(tk - 1) * 4096 + d) : zero;
    short8 x1 = (t >= 2) ? ld8(xz + (size_t)(tk - 2) * 4096 + d) : zero;
    short8 x0 = (t >= 3) ? ld8(xz + (size_t)(tk - 3) * 4096 + d) : zero;
    short8 r;
#pragma unroll
    for (int j = 0; j < 8; ++j) {
        floatx4 wv = *(const floatx4*)(cw + (size_t)(d + j) * 4);
        float acc = cb[d + j]
                  + wv[0] * bf2f(x0[j]) + wv[1] * bf2f(x1[j])
                  + wv[2] * bf2f(x2[j]) + wv[3] * bf2f(x3[j]);
        float s = acc / (1.f + __expf(-acc));
        r[j] = __builtin_bit_cast(short, f2bf(s));
    }
    *(short8*)(xcb + idx) = r;
}

// pad x_proj_w fp32 [96,2048] -> bf16 [128,2048] with zero rows (tight mode)
__launch_bounds__(256)
__global__ void padw_kernel(const float* __restrict__ w, bf16* __restrict__ wp)
{
    int idx = blockIdx.x * 256 + threadIdx.x;   // 128*2048
    int row = idx >> 11;
    wp[idx] = (row < 96) ? f2bf(w[idx]) : f2bf(0.f);
}

// ---------------------------------------------------------------------------
// Chunked selective scan, 3 phases, 8 states per thread (2 threads per (b,d)
// chain). Template NCH_: chunk count (roomy=64 for 8 blocks/CU TLP).
// ---------------------------------------------------------------------------
template<int NCH_>
__launch_bounds__(256)
__global__ void scan_part1(const bf16* __restrict__ dt, const bf16* __restrict__ xc,
                           const float* __restrict__ xdbl, const float* __restrict__ A_log,
                           float* __restrict__ Ssum, float* __restrict__ hend)
{
    constexpr int CLEN_ = LSEQ / NCH_;
    constexpr int LOGN  = (NCH_ == 64) ? 6 : 5;
    int G = blockIdx.x * 256 + threadIdx.x;     // 2 * NCH_ * DI * 2
    int half = G & 1;
    int d = (G >> 1) & (DI - 1);
    int c = (G >> 12) & (NCH_ - 1);
    int b = G >> (12 + LOGN);
    int n0 = half * 8;

    floatx4 al0 = *(const floatx4*)(A_log + d * 16 + n0);
    floatx4 al1 = *(const floatx4*)(A_log + d * 16 + n0 + 4);
    float a[8];
#pragma unroll
    for (int j = 0; j < 4; ++j) { a[j] = -__expf(al0[j]); a[j + 4] = -__expf(al1[j]); }

    const bf16*  dt_p = dt   + (size_t)b * LSEQ * DI + d;
    const bf16*  xc_p = xc   + (size_t)b * LSEQ * DI + d;
    const float* xb_p = xdbl + (size_t)b * LSEQ * 128 + 64 + n0;   // B slice

    float h[8];
#pragma unroll
    for (int j = 0; j < 8; ++j) h[j] = 0.f;
    float S = 0.f;

    const int t0 = c * CLEN_;
#pragma unroll 4
    for (int t = t0; t < t0 + CLEN_; ++t) {
        float dtv = to_f(dt_p[(size_t)t * DI]);
        float xv  = to_f(xc_p[(size_t)t * DI]);
        floatx4 B0 = *(const floatx4*)(xb_p + (size_t)t * 128);
        floatx4 B1 = *(const floatx4*)(xb_p + (size_t)t * 128 + 4);
        S += dtv;
        float dx = dtv * xv;
#pragma unroll
        for (int j = 0; j < 4; ++j) {
            h[j]     = fmaf(__expf(dtv * a[j]),     h[j],     dx * B0[j]);
            h[j + 4] = fmaf(__expf(dtv * a[j + 4]), h[j + 4], dx * B1[j]);
        }
    }

    size_t cid = (size_t)(b * NCH_ + c) * DI + d;
    if (half == 0) Ssum[cid] = S;
    float* he = hend + cid * 16 + n0;
    *(floatx4*)he       = (floatx4){h[0], h[1], h[2], h[3]};
    *(floatx4*)(he + 4) = (floatx4){h[4], h[5], h[6], h[7]};
}

template<int NCH_>
__launch_bounds__(256)
__global__ void scan_prefix(const float* __restrict__ A_log, const float* __restrict__ Ssum,
                            float* __restrict__ hend)
{
    int tid = blockIdx.x * 256 + threadIdx.x;   // 2*DI*16 = 65536
    int n = tid & 15;
    int d = (tid >> 4) & (DI - 1);
    int b = tid >> 15;
    float a = -__expf(A_log[d * 16 + n]);

    size_t row = (size_t)b * NCH_ * DI + d;
    float Sc = Ssum[row];
    float E  = hend[row * 16 + n];
    float h = 0.f;
    for (int c = 0; c < NCH_; ++c) {
        size_t nrow = row + DI;
        float Sn = 0.f, En = 0.f;
        if (c + 1 < NCH_) { Sn = Ssum[nrow]; En = hend[nrow * 16 + n]; }
        float P = __expf(a * Sc);
        hend[row * 16 + n] = h;      // becomes hinit for chunk c
        h  = fmaf(P, h, E);
        Sc = Sn; E = En; row = nrow;
    }
}

template<int NCH_>
__launch_bounds__(256)
__global__ void scan_part2(const bf16* __restrict__ dt, const bf16* __restrict__ xc,
                           const float* __restrict__ xdbl, const bf16* __restrict__ xz,
                           const float* __restrict__ hinit, const float* __restrict__ A_log,
                           const float* __restrict__ Dp, bf16* __restrict__ Y)
{
    constexpr int CLEN_ = LSEQ / NCH_;
    constexpr int LOGN  = (NCH_ == 64) ? 6 : 5;
    int G = blockIdx.x * 256 + threadIdx.x;
    int half = G & 1;
    int d = (G >> 1) & (DI - 1);
    int c = (G >> 12) & (NCH_ - 1);
    int b = G >> (12 + LOGN);
    int n0 = half * 8;

    floatx4 al0 = *(const floatx4*)(A_log + d * 16 + n0);
    floatx4 al1 = *(const floatx4*)(A_log + d * 16 + n0 + 4);
    float a[8];
#pragma unroll
    for (int j = 0; j < 4; ++j) { a[j] = -__expf(al0[j]); a[j + 4] = -__expf(al1[j]); }
    float Dd = Dp[d];

    size_t cid = (size_t)(b * NCH_ + c) * DI + d;
    const float* hi = hinit + cid * 16 + n0;
    floatx4 h0 = *(const floatx4*)hi;
    floatx4 h1 = *(const floatx4*)(hi + 4);
    float h[8] = {h0[0], h0[1], h0[2], h0[3], h1[0], h1[1], h1[2], h1[3]};

    const bf16*  dt_p = dt   + (size_t)b * LSEQ * DI + d;
    const bf16*  xc_p = xc   + (size_t)b * LSEQ * DI + d;
    const float* xb_p = xdbl + (size_t)b * LSEQ * 128 + 64 + n0;   // B slice
    const float* xcc_p= xdbl + (size_t)b * LSEQ * 128 + 80 + n0;   // C slice
    const bf16*  z_p  = xz   + (size_t)b * LSEQ * 4096 + DI + d;
    bf16* y_p = Y + (size_t)b * LSEQ * DI + d;

    const int t0 = c * CLEN_;
#pragma unroll 4
    for (int t = t0; t < t0 + CLEN_; ++t) {
        float dtv = to_f(dt_p[(size_t)t * DI]);
        float xv  = to_f(xc_p[(size_t)t * DI]);
        float zv  = to_f(z_p[(size_t)t * 4096]);
        floatx4 B0 = *(const floatx4*)(xb_p  + (size_t)t * 128);
        floatx4 B1 = *(const floatx4*)(xb_p  + (size_t)t * 128 + 4);
        floatx4 C0 = *(const floatx4*)(xcc_p + (size_t)t * 128);
        floatx4 C1 = *(const floatx4*)(xcc_p + (size_t)t * 128 + 4);
        float dx = dtv * xv;
        float p = 0.f;
#pragma unroll
        for (int j = 0; j < 4; ++j) {
            h[j]     = fmaf(__expf(dtv * a[j]),     h[j],     dx * B0[j]);
            p = fmaf(h[j], C0[j], p);
            h[j + 4] = fmaf(__expf(dtv * a[j + 4]), h[j + 4], dx * B1[j]);
            p = fmaf(h[j + 4], C1[j], p);
        }
        p += __shfl_xor(p, 1);      // combine the two 8-state halves
        if (half == 0) {
            float pp = p + Dd * xv;
            float sz = zv / (1.f + __expf(-zv));
            y_p[(size_t)t * DI] = f2bf(pp * sz);
        }
    }
}

// ---------------------------------------------------------------------------
extern "C" void kernel_launch(void* const* d_in, const int* in_sizes, int n_in,
                              void* d_out, int out_size, void* d_ws, size_t ws_size,
                              hipStream_t stream)
{
    const float* x       = (const float*)d_in[0];
    const float* in_proj = (const float*)d_in[1];
    const float* conv_w  = (const float*)d_in[2];
    const float* conv_b  = (const float*)d_in[3];
    const float* x_proj  = (const float*)d_in[4];
    const float* dt_w    = (const float*)d_in[5];
    const float* dt_b    = (const float*)d_in[6];
    const float* A_log   = (const float*)d_in[7];
    const float* Dp      = (const float*)d_in[8];
    const float* out_w   = (const float*)d_in[9];
    const float* ln1g    = (const float*)d_in[10];
    const float* ln1b    = (const float*)d_in[11];
    const float* ln2g    = (const float*)d_in[12];
    const float* ln2b    = (const float*)d_in[13];
    const float* fw1     = (const float*)d_in[14];
    const float* fb1     = (const float*)d_in[15];
    const float* fw2     = (const float*)d_in[16];
    const float* fb2     = (const float*)d_in[17];
    float* out = (float*)d_out;

    // Base workspace layout (lifetime-aliased):
    //  @0    4MB   h1 / Ssum (<=1MB)
    //  @4    16MB  xz -> Pout -> f1
    //  @20   8MB   xc (-> Y in-place)   | at ffn2: Pf @20..36
    //  @28   1MB   xdf
    //  @29   8MB   dtb                  | step5: Pp fp32 partials @29..45
    //  @37   hend (roomy NCH=64: 16MB @37..53, ipB dead by then) -> x2 @37..45
    //  @45   0.5MB Wpad
    // Roomy (ws >= 74MB): bf16 weights ipB@46 owB@54 fw1B@58 fw2B@66.
    char* w = (char*)d_ws;
    bf16*  h1   = (bf16*)(w);
    bf16*  xz   = (bf16*)(w + (4u  << 20));
    bf16*  xc   = (bf16*)(w + (20u << 20));
    float* xdf  = (float*)(w + (28u << 20));
    bf16*  dtb  = (bf16*)(w + (29u << 20));
    float* Pp   = (float*)(w + (29u << 20));   // 16MB fp32 partials (xproj)
    float* hend = (float*)(w + (37u << 20));
    float* x2   = (float*)(w + (37u << 20));
    bf16*  Wpad = (bf16*)(w + (45u << 20));
    float* Ssum = (float*)(w);
    bf16*  Pout = (bf16*)(w + (4u  << 20));    // 16MB bf16 partials (outproj)
    bf16*  Yb = xc;
    bf16*  f1 = xz;

    const bool roomy = ws_size >= ((size_t)74 << 20);

    if (roomy) {
        bf16* ipB  = (bf16*)(w + (46u << 20));   // 8MB
        bf16* owB  = (bf16*)(w + (54u << 20));   // 4MB
        bf16* fw1B = (bf16*)(w + (58u << 20));   // 8MB
        bf16* fw2B = (bf16*)(w + (66u << 20));   // 8MB
        bf16* Pf   = (bf16*)(w + (20u << 20));   // 16MB (xc/xdf/dtb dead at ffn2)

        pre_ln_cvt<<<dim3(T_TOK + 7296), dim3(256), 0, stream>>>(
            x, ln1g, ln1b, h1,
            in_proj, ipB, out_w, owB, fw1, fw1B, fw2, fw2B, x_proj, Wpad);
        g_inproj<<<dim3(16, 32), dim3(512), 0, stream>>>(h1, ipB, xz);
        conv_silu<<<dim3(T_TOK * DI / 8 / 256), dim3(256), 0, stream>>>(xz, conv_w, conv_b, xc);
        g_xproj<<<dim3(16, 1, 16), dim3(512), 0, stream>>>(xc, Wpad, Pp);
        reduce16<<<dim3(256), dim3(256), 0, stream>>>(Pp, xdf);
        gemm_dt64<<<dim3(64, 16), dim3(256), 0, stream>>>(xdf, dt_w, dt_b, dtb);
        scan_part1<64><<<dim3(2048), dim3(256), 0, stream>>>(dtb, xc, xdf, A_log, Ssum, hend);
        scan_prefix<64><<<dim3(256), dim3(256), 0, stream>>>(A_log, Ssum, hend);
        scan_part2<64><<<dim3(2048), dim3(256), 0, stream>>>(dtb, xc, xdf, xz, hend, A_log, Dp, Yb);
        g_outproj<<<dim3(16, 8, 4), dim3(512), 0, stream>>>(Yb, owB, Pout);
        red4_ln<<<dim3(T_TOK), dim3(256), 0, stream>>>(Pout, x, ln2g, ln2b, x2, h1);
        g_ffn1<<<dim3(16, 32), dim3(512), 0, stream>>>(h1, fw1B, f1, fb1);
        g_ffn2_4<<<dim3(16, 8, 4), dim3(512), 0, stream>>>(f1, fw2B, Pf);
        red_bias_resid<4><<<dim3(1024), dim3(256), 0, stream>>>(Pf, fb2, x2, out);
    } else {
        bf16* ipB  = (bf16*)(w + (20u << 20));   // pre-conv, xc region free
        bf16* owB  = (bf16*)(w);                 // post-prefix, Ssum dead
        bf16* fw1B = (bf16*)(w + (29u << 20));   // post-scan, dtb dead
        bf16* fw2B = (bf16*)(w + (20u << 20));   // post-outproj, Y dead
        bf16* Pf   = (bf16*)(w + (28u << 20));   // 8MB, KS=2 (xdf/fw1B dead)

        cvtw<<<dim3(2048), dim3(256), 0, stream>>>(in_proj, ipB);
        ln_kernel<<<dim3(T_TOK), dim3(256), 0, stream>>>(x, ln1g, ln1b, h1);
        g_inproj<<<dim3(16, 32), dim3(512), 0, stream>>>(h1, ipB, xz);
        conv_silu<<<dim3(T_TOK * DI / 8 / 256), dim3(256), 0, stream>>>(xz, conv_w, conv_b, xc);
        padw_kernel<<<dim3(128 * 2048 / 256), dim3(256), 0, stream>>>(x_proj, Wpad);
        g_xproj<<<dim3(16, 1, 16), dim3(512), 0, stream>>>(xc, Wpad, Pp);
        reduce16<<<dim3(256), dim3(256), 0, stream>>>(Pp, xdf);
        gemm_dt64<<<dim3(64, 16), dim3(256), 0, stream>>>(xdf, dt_w, dt_b, dtb);
        scan_part1<32><<<dim3(1024), dim3(256), 0, stream>>>(dtb, xc, xdf, A_log, Ssum, hend);
        scan_prefix<32><<<dim3(256), dim3(256), 0, stream>>>(A_log, Ssum, hend);
        cvtw<<<dim3(1024), dim3(256), 0, stream>>>(out_w, owB);
        scan_part2<32><<<dim3(1024), dim3(256), 0, stream>>>(dtb, xc, xdf, xz, hend, A_log, Dp, Yb);
        g_outproj<<<dim3(16, 8, 4), dim3(512), 0, stream>>>(Yb, owB, Pout);
        cvtw<<<dim3(2048), dim3(256), 0, stream>>>(fw1, fw1B);
        red4_ln<<<dim3(T_TOK), dim3(256), 0, stream>>>(Pout, x, ln2g, ln2b, x2, h1);
        g_ffn1<<<dim3(16, 32), dim3(512), 0, stream>>>(h1, fw1B, f1, fb1);
        cvtw<<<dim3(2048), dim3(256), 0, stream>>>(fw2, fw2B);
        g_ffn2_2<<<dim3(16, 8, 2), dim3(512), 0, stream>>>(f1, fw2B, Pf);
        red_bias_resid<2><<<dim3(1024), dim3(256), 0, stream>>>(Pf, fb2, x2, out);
    }
}

// Round 10
// 333.040 us; speedup vs baseline: 1.1326x; 1.0028x over previous
//
#include <hip/hip_runtime.h>
#include <hip/hip_bf16.h>

#define T_TOK 2048   // BATCH*SEQLEN
#define LSEQ  1024
#define DM    1024
#define DI    2048
#define LDW2  72     // LDS row stride for K=64 dt gemm

using bf16 = __hip_bfloat16;
typedef __attribute__((ext_vector_type(8))) short short8;
typedef __attribute__((ext_vector_type(4))) short short4b;
typedef __attribute__((ext_vector_type(4))) float floatx4;

__device__ inline float to_f(float v) { return v; }
__device__ inline float to_f(bf16 v) { return __bfloat162float(v); }
__device__ inline bf16  f2bf(float v) { return __float2bfloat16(v); }
__device__ inline float bf2f(short s) { return __bfloat162float(__builtin_bit_cast(bf16, s)); }

// load 8 contiguous elements as bf16 bit-pattern (converting if fp32 source)
__device__ inline short8 ld8(const bf16* p) { return *(const short8*)p; }
__device__ inline short8 ld8(const float* p) {
    floatx4 f0 = *(const floatx4*)p;
    floatx4 f1 = *(const floatx4*)(p + 4);
    short8 r;
#pragma unroll
    for (int i = 0; i < 4; ++i) {
        r[i]     = __builtin_bit_cast(short, __float2bfloat16(f0[i]));
        r[i + 4] = __builtin_bit_cast(short, __float2bfloat16(f1[i]));
    }
    return r;
}

// async global->LDS, 16B per lane (dest = wave-uniform base + lane*16)
__device__ __forceinline__ void gload16(const void* g, void* l) {
    __builtin_amdgcn_global_load_lds(
        (const __attribute__((address_space(1))) unsigned int*)g,
        (__attribute__((address_space(3))) unsigned int*)l, 16, 0, 0);
}

// Linear [row][64] bf16 tile (128B row = 8x16B slots) with XOR involution
// col ^= (row&7)<<3.  A quarter-wave ds_read_b128 (16 lanes, consecutive
// rows, same col) then spans all 8 slots with exactly 2 lanes each ->
// conflict-free.  Same XOR applied to the GLOBAL source column during
// staging (linear LDS dest, pre-swizzled source — rule 21).
__device__ __forceinline__ int swz64(int row, int col) {
    return row * 64 + (col ^ ((row & 7) << 3));
}

// ---------------------------------------------------------------------------
// GEMM core: C[M,N] = A[M,K] @ W[N,K]^T, both bf16. 128x128 tile, BK=64,
// 512 threads = 8 waves (wave tile 64x32, acc 4x2), global_load_lds(16B).
// T3 minimum-2-phase pipeline in PURE HIP (R8-verified):
//   prologue: STAGE(buf0); __syncthreads();
//   loop:     STAGE(buf^1, k+64); COMPUTE(buf); __syncthreads(); swap
// One barrier per K-step; prefetch HBM latency overlaps 16 MFMAs+ds_reads.
// T5: s_setprio(1) around each MFMA cluster (2-phase gives wave role-split).
// EPI: 0 bf16 | 2 bf16 softplus(c+bias) | 4 bf16 relu(c+bias)
//      7 fp32 partial @ +bz*zstr | 8 bf16 partial @ +bz*zstr
// ---------------------------------------------------------------------------
template<int EPI, int KS>
__device__ __forceinline__ void gemm_core(
    const bf16* __restrict__ A, int lda,
    const bf16* __restrict__ W, int K,
    float* __restrict__ outF, bf16* __restrict__ outB, int ldc,
    const float* __restrict__ bias, size_t zstr)
{
    __shared__ __align__(16) bf16 sA[2 * 128 * 64];
    __shared__ __align__(16) bf16 sW[2 * 128 * 64];
    const int tid  = threadIdx.x;              // 0..511
    const int lane = tid & 63, wid = tid >> 6; // 8 waves

    // bijective chunked XCD swizzle (all grids have nwg % 8 == 0)
    const int nwg = gridDim.x * gridDim.y * gridDim.z;
    const int lin = blockIdx.x + gridDim.x * (blockIdx.y + gridDim.y * blockIdx.z);
    const int sid = (lin & 7) * (nwg >> 3) + (lin >> 3);
    const int bx  = sid % gridDim.x;
    const int byz = sid / gridDim.x;
    const int by  = byz % gridDim.y;
    const int bz  = byz / gridDim.y;

    const int m0 = bx * 128, n0 = by * 128;
    const int wm = (wid >> 2) * 64;            // 2 wave-rows
    const int wn = (wid & 3) * 32;             // 4 wave-cols
    const int lr = lane & 15, lh = lane >> 4;

    // staging: issue i covers rows i*64 + (tid>>3), 8 threads/row,
    // chunk (tid&7)*8 cols, source col pre-swizzled.
    const int r0  = tid >> 3;                  // 0..63
    const int gc0 = ((tid & 7) * 8) ^ ((r0 & 7) << 3);

    const int kBeg = bz * (K / KS);
    const int kEnd = kBeg + K / KS;

    const bf16* Ag0 = A + (size_t)(m0 + r0)      * lda + kBeg + gc0;
    const bf16* Ag1 = A + (size_t)(m0 + r0 + 64) * lda + kBeg + gc0;
    const bf16* Wg0 = W + (size_t)(n0 + r0)      * K   + kBeg + gc0;
    const bf16* Wg1 = W + (size_t)(n0 + r0 + 64) * K   + kBeg + gc0;

    floatx4 acc[4][2];
#pragma unroll
    for (int i = 0; i < 4; ++i)
#pragma unroll
        for (int j = 0; j < 2; ++j) acc[i][j] = (floatx4){0.f, 0.f, 0.f, 0.f};

    // B = buffer (0/1), KOFF = k offset relative to kBeg
#define STAGE(B, KOFF) do {                                           \
        gload16(Ag0 + (KOFF), sA + (B) * 8192 + wid * 512);           \
        gload16(Ag1 + (KOFF), sA + (B) * 8192 + 4096 + wid * 512);    \
        gload16(Wg0 + (KOFF), sW + (B) * 8192 + wid * 512);           \
        gload16(Wg1 + (KOFF), sW + (B) * 8192 + 4096 + wid * 512);    \
    } while (0)

#define COMPUTE(B) do {                                                        \
        const bf16* bA = sA + (B) * 8192;                                      \
        const bf16* bW = sW + (B) * 8192;                                      \
        _Pragma("unroll")                                                      \
        for (int kk = 0; kk < 2; ++kk) {                                       \
            short8 af[4], wf[2];                                               \
            _Pragma("unroll")                                                  \
            for (int i = 0; i < 4; ++i)                                        \
                af[i] = *(const short8*)(bA + swz64(wm + i * 16 + lr,          \
                                                    kk * 32 + lh * 8));        \
            _Pragma("unroll")                                                  \
            for (int j = 0; j < 2; ++j)                                        \
                wf[j] = *(const short8*)(bW + swz64(wn + j * 16 + lr,          \
                                                    kk * 32 + lh * 8));        \
            __builtin_amdgcn_s_setprio(1);                                     \
            _Pragma("unroll")                                                  \
            for (int i = 0; i < 4; ++i)                                        \
                _Pragma("unroll")                                              \
                for (int j = 0; j < 2; ++j)                                    \
                    acc[i][j] = __builtin_amdgcn_mfma_f32_16x16x32_bf16(       \
                        af[i], wf[j], acc[i][j], 0, 0, 0);                     \
            __builtin_amdgcn_s_setprio(0);                                     \
        }                                                                      \
    } while (0)

    // prologue
    STAGE(0, 0);
    __syncthreads();
    // main loop, unrolled x2 for compile-time buffer parity (steps even)
    for (int k0 = kBeg; k0 < kEnd; k0 += 128) {
        int koff = k0 - kBeg;
        if (k0 + 64 < kEnd) STAGE(1, koff + 64);
        COMPUTE(0);
        __syncthreads();
        if (k0 + 128 < kEnd) STAGE(0, koff + 128);
        COMPUTE(1);
        __syncthreads();
    }
#undef STAGE
#undef COMPUTE

    // epilogue: C/D layout col=lane&15, row=(lane>>4)*4+reg
#pragma unroll
    for (int i = 0; i < 4; ++i) {
#pragma unroll
        for (int j = 0; j < 2; ++j) {
#pragma unroll
            for (int r = 0; r < 4; ++r) {
                int row = m0 + wm + i * 16 + lh * 4 + r;
                int col = n0 + wn + j * 16 + lr;
                size_t off = (size_t)row * ldc + col;
                float c = acc[i][j][r];
                if (EPI == 0) {
                    outB[off] = f2bf(c);
                } else if (EPI == 2) {
                    float v = c + bias[col];
                    outB[off] = f2bf((v > 15.f) ? v : log1pf(__expf(v)));
                } else if (EPI == 4) {
                    float v = c + bias[col];
                    outB[off] = f2bf(v > 0.f ? v : 0.f);
                } else if (EPI == 7) {
                    outF[off + (size_t)bz * zstr] = c;
                } else if (EPI == 8) {
                    outB[off + (size_t)bz * zstr] = f2bf(c);
                }
            }
        }
    }
}

// named wrappers (distinct symbols -> distinct rocprof rows)
__launch_bounds__(512, 4)
__global__ void g_inproj(const bf16* __restrict__ A, const bf16* __restrict__ W,
                         bf16* __restrict__ outB)
{ gemm_core<0, 1>(A, DM, W, DM, nullptr, outB, 4096, nullptr, 0); }

__launch_bounds__(512, 4)
__global__ void g_xproj(const bf16* __restrict__ A, const bf16* __restrict__ W,
                        float* __restrict__ outF)
{ gemm_core<7, 16>(A, DI, W, DI, outF, nullptr, 128, nullptr, (size_t)T_TOK * 128); }

__launch_bounds__(512, 4)
__global__ void g_outproj(const bf16* __restrict__ A, const bf16* __restrict__ W,
                          bf16* __restrict__ outB)
{ gemm_core<8, 4>(A, DI, W, DI, nullptr, outB, DM, nullptr, (size_t)T_TOK * DM); }

__launch_bounds__(512, 4)
__global__ void g_ffn1(const bf16* __restrict__ A, const bf16* __restrict__ W,
                       bf16* __restrict__ outB, const float* __restrict__ bias)
{ gemm_core<4, 1>(A, DM, W, DM, nullptr, outB, 4096, bias, 0); }

__launch_bounds__(512, 4)
__global__ void g_ffn2_4(const bf16* __restrict__ A, const bf16* __restrict__ W,
                         bf16* __restrict__ outB)
{ gemm_core<8, 4>(A, 4096, W, 4096, nullptr, outB, DM, nullptr, (size_t)T_TOK * DM); }

__launch_bounds__(512, 4)
__global__ void g_ffn2_2(const bf16* __restrict__ A, const bf16* __restrict__ W,
                         bf16* __restrict__ outB)
{ gemm_core<8, 2>(A, 4096, W, 4096, nullptr, outB, DM, nullptr, (size_t)T_TOK * DM); }

// fp32 -> bf16 weight conversion (8 elems/thread)
__launch_bounds__(256)
__global__ void cvtw(const float* __restrict__ src, bf16* __restrict__ dst)
{
    size_t i = ((size_t)blockIdx.x * 256 + threadIdx.x) * 8;
    *(short8*)(dst + i) = ld8(src + i);
}

// ---------------------------------------------------------------------------
// Fused LN1 + 4-weight conversion + x_proj pad (roomy mode; ONE launch).
// Blocks [0, T_TOK): LayerNorm of token t.  Blocks [T_TOK, T_TOK+7296): cvt.
// ---------------------------------------------------------------------------
__launch_bounds__(256)
__global__ void pre_ln_cvt(const float* __restrict__ x, const float* __restrict__ g,
                           const float* __restrict__ bb, bf16* __restrict__ h1,
                           const float* __restrict__ s0, bf16* __restrict__ d0,
                           const float* __restrict__ s1, bf16* __restrict__ d1,
                           const float* __restrict__ s2, bf16* __restrict__ d2,
                           const float* __restrict__ s3, bf16* __restrict__ d3,
                           const float* __restrict__ s4, bf16* __restrict__ d4)
{
    int blk = blockIdx.x, tid = threadIdx.x;
    if (blk < T_TOK) {
        const float* xr = x + (size_t)blk * DM;
        float v[4], s = 0.f, ss = 0.f;
#pragma unroll
        for (int i = 0; i < 4; ++i) {
            v[i] = xr[tid + i * 256];
            s += v[i]; ss += v[i] * v[i];
        }
#pragma unroll
        for (int o = 1; o < 64; o <<= 1) { s += __shfl_xor(s, o); ss += __shfl_xor(ss, o); }
        __shared__ float red[8];
        int lane = tid & 63, wid = tid >> 6;
        if (lane == 0) { red[wid] = s; red[wid + 4] = ss; }
        __syncthreads();
        s  = red[0] + red[1] + red[2] + red[3];
        ss = red[4] + red[5] + red[6] + red[7];
        float mu  = s * (1.f / DM);
        float var = ss * (1.f / DM) - mu * mu;
        float rs  = rsqrtf(var + 1e-5f);
#pragma unroll
        for (int i = 0; i < 4; ++i) {
            int c = tid + i * 256;
            h1[(size_t)blk * DM + c] = f2bf((v[i] - mu) * rs * g[c] + bb[c]);
        }
        return;
    }
    constexpr size_t N0 = (size_t)2 * DI * DM;   // in_proj
    constexpr size_t N1 = (size_t)DM * DI;       // out_w
    constexpr size_t N2 = (size_t)4 * DM * DM;   // fw1
    constexpr size_t N3 = (size_t)DM * 4 * DM;   // fw2
    size_t i = ((size_t)(blk - T_TOK) * 256 + tid) * 8;
    if (i < N0) { *(short8*)(d0 + i) = ld8(s0 + i); return; }
    i -= N0;
    if (i < N1) { *(short8*)(d1 + i) = ld8(s1 + i); return; }
    i -= N1;
    if (i < N2) { *(short8*)(d2 + i) = ld8(s2 + i); return; }
    i -= N2;
    if (i < N3) { *(short8*)(d3 + i) = ld8(s3 + i); return; }
    i -= N3;
    // x_proj pad: [96,2048] fp32 -> [128,2048] bf16, zero rows >= 96
    int row = (int)(i >> 11);
    if (row < 96) { *(short8*)(d4 + i) = ld8(s4 + i); }
    else { *(short8*)(d4 + i) = (short8){0,0,0,0,0,0,0,0}; }
}

// ---------------------------------------------------------------------------
// dt GEMM, specialized: dtb = softplus(sum_z Pp[z][:, :64] @ dt_w^T + dt_b)
// A is reduced INLINE from the 16 fp32 split-K partial slices during staging
// (32 extra loads/thread, 16x L2-reused across n-blocks) — same fp32 sum
// order as the old reduce16, so results are bitwise identical.
// M=2048, N=2048, K=64. BM=32, BN=128 -> grid (64,16)=1024 blocks.
// ---------------------------------------------------------------------------
__launch_bounds__(256)
__global__ void gemm_dt64(const float* __restrict__ Pp,  // [16][2048][128] fp32
                          const float* __restrict__ W,   // dt_w [2048,64]
                          const float* __restrict__ bias,
                          bf16* __restrict__ outB)       // dtb [2048,2048]
{
    __shared__ __align__(16) bf16 sA[32 * LDW2];
    __shared__ __align__(16) bf16 sW[128 * LDW2];
    const int tid = threadIdx.x;
    const int lane = tid & 63, w = tid >> 6;
    const int m0 = blockIdx.x * 32, n0 = blockIdx.y * 128;

    {   // stage A: 32 rows x 64 cols; sum 16 partial slices inline
        int ar = tid >> 3, ac = (tid & 7) * 8;
        const float* Ap = Pp + (size_t)(m0 + ar) * 128 + ac;
        floatx4 a0 = (floatx4){0.f, 0.f, 0.f, 0.f};
        floatx4 a1 = (floatx4){0.f, 0.f, 0.f, 0.f};
#pragma unroll
        for (int z = 0; z < 16; ++z) {
            a0 += *(const floatx4*)(Ap + (size_t)z * T_TOK * 128);
            a1 += *(const floatx4*)(Ap + (size_t)z * T_TOK * 128 + 4);
        }
        short8 r;
#pragma unroll
        for (int i = 0; i < 4; ++i) {
            r[i]     = __builtin_bit_cast(short, __float2bfloat16(a0[i]));
            r[i + 4] = __builtin_bit_cast(short, __float2bfloat16(a1[i]));
        }
        *(short8*)(sA + ar * LDW2 + ac) = r;
        // stage W: 128 rows x 64 cols (4 ld8/thread)
        int wr = tid >> 1, wc = (tid & 1) * 32;
        const float* wp = W + (size_t)(n0 + wr) * 64 + wc;
        *(short8*)(sW + wr * LDW2 + wc)      = ld8(wp);
        *(short8*)(sW + wr * LDW2 + wc + 8)  = ld8(wp + 8);
        *(short8*)(sW + wr * LDW2 + wc + 16) = ld8(wp + 16);
        *(short8*)(sW + wr * LDW2 + wc + 24) = ld8(wp + 24);
    }
    __syncthreads();

    const int lr = lane & 15, lh = lane >> 4;
    floatx4 acc[2][2];
#pragma unroll
    for (int i = 0; i < 2; ++i)
#pragma unroll
        for (int j = 0; j < 2; ++j) acc[i][j] = (floatx4){0.f, 0.f, 0.f, 0.f};

#pragma unroll
    for (int kk = 0; kk < 2; ++kk) {
        short8 af[2], wf[2];
#pragma unroll
        for (int i = 0; i < 2; ++i)
            af[i] = *(const short8*)(sA + (i * 16 + lr) * LDW2 + kk * 32 + lh * 8);
#pragma unroll
        for (int j = 0; j < 2; ++j)
            wf[j] = *(const short8*)(sW + (w * 32 + j * 16 + lr) * LDW2 + kk * 32 + lh * 8);
#pragma unroll
        for (int i = 0; i < 2; ++i)
#pragma unroll
            for (int j = 0; j < 2; ++j)
                acc[i][j] = __builtin_amdgcn_mfma_f32_16x16x32_bf16(af[i], wf[j], acc[i][j], 0, 0, 0);
    }

#pragma unroll
    for (int i = 0; i < 2; ++i) {
#pragma unroll
        for (int j = 0; j < 2; ++j) {
#pragma unroll
            for (int r = 0; r < 4; ++r) {
                int row = m0 + i * 16 + lh * 4 + r;
                int col = n0 + w * 32 + j * 16 + lr;
                float v = acc[i][j][r] + bias[col];
                outB[(size_t)row * DI + col] = f2bf((v > 15.f) ? v : log1pf(__expf(v)));
            }
        }
    }
}

// sum the 16 split-K fp32 partial slices -> xdf, B/C columns 64..96 ONLY
// (cols 0..64 are consumed in-place by gemm_dt64; 96..128 is padding)
__launch_bounds__(256)
__global__ void reduce_bc(const float* __restrict__ P, float* __restrict__ out)
{
    int i = blockIdx.x * 256 + threadIdx.x;    // 2048 rows x 8 float4 = 16384
    int row = i >> 3;
    int col = 64 + (i & 7) * 4;
    size_t off = (size_t)row * 128 + col;
    floatx4 s = (floatx4){0.f, 0.f, 0.f, 0.f};
#pragma unroll
    for (int z = 0; z < 16; ++z) s += *(const floatx4*)(P + (size_t)z * T_TOK * 128 + off);
    *(floatx4*)(out + off) = s;
}

// Fused: x2 = x + sum_{z<4} P[z] ; h1 = LayerNorm(x2; g,b).  Block per token.
__launch_bounds__(256)
__global__ void red4_ln(const bf16* __restrict__ P, const float* __restrict__ x,
                        const float* __restrict__ g, const float* __restrict__ bb,
                        float* __restrict__ x2, bf16* __restrict__ h1)
{
    int t = blockIdx.x, tid = threadIdx.x;
    size_t rowoff = (size_t)t * DM + tid * 4;
    floatx4 xv = *(const floatx4*)(x + rowoff);
    float v[4];
#pragma unroll
    for (int i = 0; i < 4; ++i) v[i] = xv[i];
#pragma unroll
    for (int z = 0; z < 4; ++z) {
        short4b p = *(const short4b*)(P + (size_t)z * T_TOK * DM + rowoff);
#pragma unroll
        for (int i = 0; i < 4; ++i) v[i] += bf2f(p[i]);
    }
    *(floatx4*)(x2 + rowoff) = (floatx4){v[0], v[1], v[2], v[3]};
    float s = v[0] + v[1] + v[2] + v[3];
    float ss = v[0]*v[0] + v[1]*v[1] + v[2]*v[2] + v[3]*v[3];
#pragma unroll
    for (int o = 1; o < 64; o <<= 1) { s += __shfl_xor(s, o); ss += __shfl_xor(ss, o); }
    __shared__ float red[8];
    int lane = tid & 63, wid = tid >> 6;
    if (lane == 0) { red[wid] = s; red[wid + 4] = ss; }
    __syncthreads();
    s  = red[0] + red[1] + red[2] + red[3];
    ss = red[4] + red[5] + red[6] + red[7];
    float mu  = s * (1.f / DM);
    float var = ss * (1.f / DM) - mu * mu;
    float rs  = rsqrtf(var + 1e-5f);
    int c = tid * 4;
    short4b o4;
#pragma unroll
    for (int i = 0; i < 4; ++i)
        o4[i] = __builtin_bit_cast(short, f2bf((v[i] - mu) * rs * g[c + i] + bb[c + i]));
    *(short4b*)(h1 + rowoff) = o4;
}

// out = bias[col] + resid + sum_{z<Z} P[z]
template<int Z>
__launch_bounds__(256)
__global__ void red_bias_resid(const bf16* __restrict__ P, const float* __restrict__ bias,
                               const float* __restrict__ resid, float* __restrict__ out)
{
    size_t base = ((size_t)blockIdx.x * 256 + threadIdx.x) * 8;
    int c = (int)(base & (DM - 1));
    floatx4 b0 = *(const floatx4*)(bias + c);
    floatx4 b1 = *(const floatx4*)(bias + c + 4);
    floatx4 x0 = *(const floatx4*)(resid + base);
    floatx4 x1 = *(const floatx4*)(resid + base + 4);
    float s[8];
#pragma unroll
    for (int j = 0; j < 4; ++j) { s[j] = x0[j] + b0[j]; s[j + 4] = x1[j] + b1[j]; }
#pragma unroll
    for (int z = 0; z < Z; ++z) {
        short8 p = *(const short8*)(P + (size_t)z * T_TOK * DM + base);
#pragma unroll
        for (int j = 0; j < 8; ++j) s[j] += bf2f(p[j]);
    }
    *(floatx4*)(out + base)     = (floatx4){s[0], s[1], s[2], s[3]};
    *(floatx4*)(out + base + 4) = (floatx4){s[4], s[5], s[6], s[7]};
}

// ---------------------------------------------------------------------------
// LayerNorm over 1024 dims (fp32 in/params), one block per token, bf16 out
// (tight mode only; roomy uses pre_ln_cvt)
// ---------------------------------------------------------------------------
__launch_bounds__(256)
__global__ void ln_kernel(const float* __restrict__ x, const float* __restrict__ g,
                          const float* __restrict__ bb, bf16* __restrict__ out)
{
    int t = blockIdx.x, tid = threadIdx.x;
    const float* xr = x + (size_t)t * DM;
    float v[4], s = 0.f, ss = 0.f;
#pragma unroll
    for (int i = 0; i < 4; ++i) {
        v[i] = xr[tid + i * 256];
        s += v[i]; ss += v[i] * v[i];
    }
#pragma unroll
    for (int o = 1; o < 64; o <<= 1) { s += __shfl_xor(s, o); ss += __shfl_xor(ss, o); }
    __shared__ float red[8];
    int lane = tid & 63, wid = tid >> 6;
    if (lane == 0) { red[wid] = s; red[wid + 4] = ss; }
    __syncthreads();
    s  = red[0] + red[1] + red[2] + red[3];
    ss = red[4] + red[5] + red[6] + red[7];
    float mu  = s * (1.f / DM);
    float var = ss * (1.f / DM) - mu * mu;
    float rs  = rsqrtf(var + 1e-5f);
#pragma unroll
    for (int i = 0; i < 4; ++i) {
        int c = tid + i * 256;
        out[(size_t)t * DM + c] = f2bf((v[i] - mu) * rs * g[c] + bb[c]);
    }
}

// ---------------------------------------------------------------------------
// depthwise causal conv (k=4, fp32 weights) + bias + SiLU -> bf16.
// Vectorized: 8 consecutive d per thread (4x short8 loads, 1x short8 store).
// ---------------------------------------------------------------------------
__launch_bounds__(256)
__global__ void conv_silu(const bf16* __restrict__ xz, const float* __restrict__ cw,
                          const float* __restrict__ cb, bf16* __restrict__ xcb)
{
    int idx = (blockIdx.x * 256 + threadIdx.x) * 8;   // T_TOK*DI elems
    int d  = idx & (DI - 1);
    int tk = idx >> 11;
    int t  = tk & (LSEQ - 1);
    const short8 zero = {0, 0, 0, 0, 0, 0, 0, 0};
    short8 x3 = ld8(xz + (size_t)tk * 4096 + d);
    short8 x2 = (t >= 1) ? ld8(xz + (size_t)(tk - 1) * 4096 + d) : zero;
    short8 x1 = (t >= 2) ? ld8(xz + (size_t)(tk - 2) * 4096 + d) : zero;
    short8 x0 = (t >= 3) ? ld8(xz + (size_t)(tk - 3) * 4096 + d) : zero;
    short8 r;
#pragma unroll
    for (int j = 0; j < 8; ++j) {
        floatx4 wv = *(const floatx4*)(cw + (size_t)(d + j) * 4);
        float acc = cb[d + j]
                  + wv[0] * bf2f(x0[j]) + wv[1] * bf2f(x1[j])
                  + wv[2] * bf2f(x2[j]) + wv[3] * bf2f(x3[j]);
        float s = acc / (1.f + __expf(-acc));
        r[j] = __builtin_bit_cast(short, f2bf(s));
    }
    *(short8*)(xcb + idx) = r;
}

// pad x_proj_w fp32 [96,2048] -> bf16 [128,2048] with zero rows (tight mode)
__launch_bounds__(256)
__global__ void padw_kernel(const float* __restrict__ w, bf16* __restrict__ wp)
{
    int idx = blockIdx.x * 256 + threadIdx.x;   // 128*2048
    int row = idx >> 11;
    wp[idx] = (row < 96) ? f2bf(w[idx]) : f2bf(0.f);
}

// ---------------------------------------------------------------------------
// Chunked selective scan, 3 phases, 8 states per thread (2 threads per (b,d)
// chain). Template NCH_: chunk count (roomy=64 for 8 blocks/CU TLP).
// ---------------------------------------------------------------------------
template<int NCH_>
__launch_bounds__(256)
__global__ void scan_part1(const bf16* __restrict__ dt, const bf16* __restrict__ xc,
                           const float* __restrict__ xdbl, const float* __restrict__ A_log,
                           float* __restrict__ Ssum, float* __restrict__ hend)
{
    constexpr int CLEN_ = LSEQ / NCH_;
    constexpr int LOGN  = (NCH_ == 64) ? 6 : 5;
    int G = blockIdx.x * 256 + threadIdx.x;     // 2 * NCH_ * DI * 2
    int half = G & 1;
    int d = (G >> 1) & (DI - 1);
    int c = (G >> 12) & (NCH_ - 1);
    int b = G >> (12 + LOGN);
    int n0 = half * 8;

    floatx4 al0 = *(const floatx4*)(A_log + d * 16 + n0);
    floatx4 al1 = *(const floatx4*)(A_log + d * 16 + n0 + 4);
    float a[8];
#pragma unroll
    for (int j = 0; j < 4; ++j) { a[j] = -__expf(al0[j]); a[j + 4] = -__expf(al1[j]); }

    const bf16*  dt_p = dt   + (size_t)b * LSEQ * DI + d;
    const bf16*  xc_p = xc   + (size_t)b * LSEQ * DI + d;
    const float* xb_p = xdbl + (size_t)b * LSEQ * 128 + 64 + n0;   // B slice

    float h[8];
#pragma unroll
    for (int j = 0; j < 8; ++j) h[j] = 0.f;
    float S = 0.f;

    const int t0 = c * CLEN_;
#pragma unroll 4
    for (int t = t0; t < t0 + CLEN_; ++t) {
        float dtv = to_f(dt_p[(size_t)t * DI]);
        float xv  = to_f(xc_p[(size_t)t * DI]);
        floatx4 B0 = *(const floatx4*)(xb_p + (size_t)t * 128);
        floatx4 B1 = *(const floatx4*)(xb_p + (size_t)t * 128 + 4);
        S += dtv;
        float dx = dtv * xv;
#pragma unroll
        for (int j = 0; j < 4; ++j) {
            h[j]     = fmaf(__expf(dtv * a[j]),     h[j],     dx * B0[j]);
            h[j + 4] = fmaf(__expf(dtv * a[j + 4]), h[j + 4], dx * B1[j]);
        }
    }

    size_t cid = (size_t)(b * NCH_ + c) * DI + d;
    if (half == 0) Ssum[cid] = S;
    float* he = hend + cid * 16 + n0;
    *(floatx4*)he       = (floatx4){h[0], h[1], h[2], h[3]};
    *(floatx4*)(he + 4) = (floatx4){h[4], h[5], h[6], h[7]};
}

template<int NCH_>
__launch_bounds__(256)
__global__ void scan_prefix(const float* __restrict__ A_log, const float* __restrict__ Ssum,
                            float* __restrict__ hend)
{
    int tid = blockIdx.x * 256 + threadIdx.x;   // 2*DI*16 = 65536
    int n = tid & 15;
    int d = (tid >> 4) & (DI - 1);
    int b = tid >> 15;
    float a = -__expf(A_log[d * 16 + n]);

    size_t row = (size_t)b * NCH_ * DI + d;
    float Sc = Ssum[row];
    float E  = hend[row * 16 + n];
    float h = 0.f;
    for (int c = 0; c < NCH_; ++c) {
        size_t nrow = row + DI;
        float Sn = 0.f, En = 0.f;
        if (c + 1 < NCH_) { Sn = Ssum[nrow]; En = hend[nrow * 16 + n]; }
        float P = __expf(a * Sc);
        hend[row * 16 + n] = h;      // becomes hinit for chunk c
        h  = fmaf(P, h, E);
        Sc = Sn; E = En; row = nrow;
    }
}

template<int NCH_>
__launch_bounds__(256)
__global__ void scan_part2(const bf16* __restrict__ dt, const bf16* __restrict__ xc,
                           const float* __restrict__ xdbl, const bf16* __restrict__ xz,
                           const float* __restrict__ hinit, const float* __restrict__ A_log,
                           const float* __restrict__ Dp, bf16* __restrict__ Y)
{
    constexpr int CLEN_ = LSEQ / NCH_;
    constexpr int LOGN  = (NCH_ == 64) ? 6 : 5;
    int G = blockIdx.x * 256 + threadIdx.x;
    int half = G & 1;
    int d = (G >> 1) & (DI - 1);
    int c = (G >> 12) & (NCH_ - 1);
    int b = G >> (12 + LOGN);
    int n0 = half * 8;

    floatx4 al0 = *(const floatx4*)(A_log + d * 16 + n0);
    floatx4 al1 = *(const floatx4*)(A_log + d * 16 + n0 + 4);
    float a[8];
#pragma unroll
    for (int j = 0; j < 4; ++j) { a[j] = -__expf(al0[j]); a[j + 4] = -__expf(al1[j]); }
    float Dd = Dp[d];

    size_t cid = (size_t)(b * NCH_ + c) * DI + d;
    const float* hi = hinit + cid * 16 + n0;
    floatx4 h0 = *(const floatx4*)hi;
    floatx4 h1 = *(const floatx4*)(hi + 4);
    float h[8] = {h0[0], h0[1], h0[2], h0[3], h1[0], h1[1], h1[2], h1[3]};

    const bf16*  dt_p = dt   + (size_t)b * LSEQ * DI + d;
    const bf16*  xc_p = xc   + (size_t)b * LSEQ * DI + d;
    const float* xb_p = xdbl + (size_t)b * LSEQ * 128 + 64 + n0;   // B slice
    const float* xcc_p= xdbl + (size_t)b * LSEQ * 128 + 80 + n0;   // C slice
    const bf16*  z_p  = xz   + (size_t)b * LSEQ * 4096 + DI + d;
    bf16* y_p = Y + (size_t)b * LSEQ * DI + d;

    const int t0 = c * CLEN_;
#pragma unroll 4
    for (int t = t0; t < t0 + CLEN_; ++t) {
        float dtv = to_f(dt_p[(size_t)t * DI]);
        float xv  = to_f(xc_p[(size_t)t * DI]);
        float zv  = to_f(z_p[(size_t)t * 4096]);
        floatx4 B0 = *(const floatx4*)(xb_p  + (size_t)t * 128);
        floatx4 B1 = *(const floatx4*)(xb_p  + (size_t)t * 128 + 4);
        floatx4 C0 = *(const floatx4*)(xcc_p + (size_t)t * 128);
        floatx4 C1 = *(const floatx4*)(xcc_p + (size_t)t * 128 + 4);
        float dx = dtv * xv;
        float p = 0.f;
#pragma unroll
        for (int j = 0; j < 4; ++j) {
            h[j]     = fmaf(__expf(dtv * a[j]),     h[j],     dx * B0[j]);
            p = fmaf(h[j], C0[j], p);
            h[j + 4] = fmaf(__expf(dtv * a[j + 4]), h[j + 4], dx * B1[j]);
            p = fmaf(h[j + 4], C1[j], p);
        }
        p += __shfl_xor(p, 1);      // combine the two 8-state halves
        if (half == 0) {
            float pp = p + Dd * xv;
            float sz = zv / (1.f + __expf(-zv));
            y_p[(size_t)t * DI] = f2bf(pp * sz);
        }
    }
}

// ---------------------------------------------------------------------------
extern "C" void kernel_launch(void* const* d_in, const int* in_sizes, int n_in,
                              void* d_out, int out_size, void* d_ws, size_t ws_size,
                              hipStream_t stream)
{
    const float* x       = (const float*)d_in[0];
    const float* in_proj = (const float*)d_in[1];
    const float* conv_w  = (const float*)d_in[2];
    const float* conv_b  = (const float*)d_in[3];
    const float* x_proj  = (const float*)d_in[4];
    const float* dt_w    = (const float*)d_in[5];
    const float* dt_b    = (const float*)d_in[6];
    const float* A_log   = (const float*)d_in[7];
    const float* Dp      = (const float*)d_in[8];
    const float* out_w   = (const float*)d_in[9];
    const float* ln1g    = (const float*)d_in[10];
    const float* ln1b    = (const float*)d_in[11];
    const float* ln2g    = (const float*)d_in[12];
    const float* ln2b    = (const float*)d_in[13];
    const float* fw1     = (const float*)d_in[14];
    const float* fb1     = (const float*)d_in[15];
    const float* fw2     = (const float*)d_in[16];
    const float* fb2     = (const float*)d_in[17];
    float* out = (float*)d_out;

    // Base workspace layout (lifetime-aliased):
    //  @0    4MB   h1 / Ssum (<=1MB)
    //  @4    16MB  xz -> Pout -> f1
    //  @20   8MB   xc (-> Y in-place)   | at ffn2: Pf @20..36
    //  @28   1MB   xdf (B/C cols only)
    //  @29   8MB   dtb                  | step5: Pp fp32 partials @29..45
    //  @37   hend (roomy NCH=64: 16MB @37..53, ipB dead by then) -> x2 @37..45
    //  @45   0.5MB Wpad
    // Roomy (ws >= 74MB): bf16 weights ipB@46 owB@54 fw1B@58 fw2B@66.
    char* w = (char*)d_ws;
    bf16*  h1   = (bf16*)(w);
    bf16*  xz   = (bf16*)(w + (4u  << 20));
    bf16*  xc   = (bf16*)(w + (20u << 20));
    float* xdf  = (float*)(w + (28u << 20));
    bf16*  dtb  = (bf16*)(w + (29u << 20));
    float* Pp   = (float*)(w + (29u << 20));   // 16MB fp32 partials (xproj)
    float* hend = (float*)(w + (37u << 20));
    float* x2   = (float*)(w + (37u << 20));
    bf16*  Wpad = (bf16*)(w + (45u << 20));
    float* Ssum = (float*)(w);
    bf16*  Pout = (bf16*)(w + (4u  << 20));    // 16MB bf16 partials (outproj)
    bf16*  Yb = xc;
    bf16*  f1 = xz;

    const bool roomy = ws_size >= ((size_t)74 << 20);

    if (roomy) {
        bf16* ipB  = (bf16*)(w + (46u << 20));   // 8MB
        bf16* owB  = (bf16*)(w + (54u << 20));   // 4MB
        bf16* fw1B = (bf16*)(w + (58u << 20));   // 8MB
        bf16* fw2B = (bf16*)(w + (66u << 20));   // 8MB
        bf16* Pf   = (bf16*)(w + (20u << 20));   // 16MB (xc/xdf/dtb dead at ffn2)

        pre_ln_cvt<<<dim3(T_TOK + 7296), dim3(256), 0, stream>>>(
            x, ln1g, ln1b, h1,
            in_proj, ipB, out_w, owB, fw1, fw1B, fw2, fw2B, x_proj, Wpad);
        g_inproj<<<dim3(16, 32), dim3(512), 0, stream>>>(h1, ipB, xz);
        conv_silu<<<dim3(T_TOK * DI / 8 / 256), dim3(256), 0, stream>>>(xz, conv_w, conv_b, xc);
        g_xproj<<<dim3(16, 1, 16), dim3(512), 0, stream>>>(xc, Wpad, Pp);
        reduce_bc<<<dim3(64), dim3(256), 0, stream>>>(Pp, xdf);
        gemm_dt64<<<dim3(64, 16), dim3(256), 0, stream>>>(Pp, dt_w, dt_b, dtb);
        scan_part1<64><<<dim3(2048), dim3(256), 0, stream>>>(dtb, xc, xdf, A_log, Ssum, hend);
        scan_prefix<64><<<dim3(256), dim3(256), 0, stream>>>(A_log, Ssum, hend);
        scan_part2<64><<<dim3(2048), dim3(256), 0, stream>>>(dtb, xc, xdf, xz, hend, A_log, Dp, Yb);
        g_outproj<<<dim3(16, 8, 4), dim3(512), 0, stream>>>(Yb, owB, Pout);
        red4_ln<<<dim3(T_TOK), dim3(256), 0, stream>>>(Pout, x, ln2g, ln2b, x2, h1);
        g_ffn1<<<dim3(16, 32), dim3(512), 0, stream>>>(h1, fw1B, f1, fb1);
        g_ffn2_4<<<dim3(16, 8, 4), dim3(512), 0, stream>>>(f1, fw2B, Pf);
        red_bias_resid<4><<<dim3(1024), dim3(256), 0, stream>>>(Pf, fb2, x2, out);
    } else {
        bf16* ipB  = (bf16*)(w + (20u << 20));   // pre-conv, xc region free
        bf16* owB  = (bf16*)(w);                 // post-prefix, Ssum dead
        bf16* fw1B = (bf16*)(w + (29u << 20));   // post-scan, dtb dead
        bf16* fw2B = (bf16*)(w + (20u << 20));   // post-outproj, Y dead
        bf16* Pf   = (bf16*)(w + (28u << 20));   // 8MB, KS=2 (xdf/fw1B dead)

        cvtw<<<dim3(2048), dim3(256), 0, stream>>>(in_proj, ipB);
        ln_kernel<<<dim3(T_TOK), dim3(256), 0, stream>>>(x, ln1g, ln1b, h1);
        g_inproj<<<dim3(16, 32), dim3(512), 0, stream>>>(h1, ipB, xz);
        conv_silu<<<dim3(T_TOK * DI / 8 / 256), dim3(256), 0, stream>>>(xz, conv_w, conv_b, xc);
        padw_kernel<<<dim3(128 * 2048 / 256), dim3(256), 0, stream>>>(x_proj, Wpad);
        g_xproj<<<dim3(16, 1, 16), dim3(512), 0, stream>>>(xc, Wpad, Pp);
        reduce_bc<<<dim3(64), dim3(256), 0, stream>>>(Pp, xdf);
        gemm_dt64<<<dim3(64, 16), dim3(256), 0, stream>>>(Pp, dt_w, dt_b, dtb);
        scan_part1<32><<<dim3(1024), dim3(256), 0, stream>>>(dtb, xc, xdf, A_log, Ssum, hend);
        scan_prefix<32><<<dim3(256), dim3(256), 0, stream>>>(A_log, Ssum, hend);
        cvtw<<<dim3(1024), dim3(256), 0, stream>>>(out_w, owB);
        scan_part2<32><<<dim3(1024), dim3(256), 0, stream>>>(dtb, xc, xdf, xz, hend, A_log, Dp, Yb);
        g_outproj<<<dim3(16, 8, 4), dim3(512), 0, stream>>>(Yb, owB, Pout);
        cvtw<<<dim3(2048), dim3(256), 0, stream>>>(fw1, fw1B);
        red4_ln<<<dim3(T_TOK), dim3(256), 0, stream>>>(Pout, x, ln2g, ln2b, x2, h1);
        g_ffn1<<<dim3(16, 32), dim3(512), 0, stream>>>(h1, fw1B, f1, fb1);
        cvtw<<<dim3(2048), dim3(256), 0, stream>>>(fw2, fw2B);
        g_ffn2_2<<<dim3(16, 8, 2), dim3(512), 0, stream>>>(f1, fw2B, Pf);
        red_bias_resid<2><<<dim3(1024), dim3(256), 0, stream>>>(Pf, fb2, x2, out);
    }
}